// Round 8
// baseline (549.831 us; speedup 1.0000x reference)
//
#include <hip/hip_runtime.h>
#include <hip/hip_bf16.h>
#include <math.h>

#define NN 50000
#define EE 800000
#define MPAD 50048          // 64-aligned row pad for MFMA GEMMs

// ---------- workspace layout (offsets in floats) ----------
#define OFF_QQBF   0ull          // MPAD*512 bf16 = 12,812,288 fl
#define OFF_KVBF   12900000ull   // MPAD*512 bf16
#define OFF_AGGBF  25900000ull   // MPAD*512 bf16
#define OFF_MSGF   38800000ull   // MPAD*128 fp32 = 6,406,144 fl
#define OFF_MSGBF  45300000ull   // MPAD*128 bf16 = 3,203,072 fl
#define OFF_INT    48600000ull   // ints: 3N+2+2E = 1,750,002
#define OFF_WCATQ  50500000ull   // 128*512 fp32
#define OFF_WCATKV 50600000ull
#define OFF_WBIG   50700000ull   // 512*128 fp32
#define OFF_WGRU   50800000ull   // 256*512 fp32
#define OFF_BCATQ  51000000ull   // 512
#define OFF_BCATKV 51001000ull   // 512
#define OFF_BGRU   51002000ull   // 512
#define OFF_PQ     51010000ull   // packed bf16
#define OFF_PKV    51050000ull
#define OFF_PBIG   51090000ull
#define OFF_PGRU   51130000ull   // 131072 shorts
#define OFF_X0BF   51200000ull   // MPAD*128 bf16 = 3,203,072 fl
// end ~54.41M floats = 218 MB

typedef short bf16x8 __attribute__((ext_vector_type(8)));
typedef float f32x4 __attribute__((ext_vector_type(4)));
typedef float fv4 __attribute__((ext_vector_type(4)));    // native vec for nontemporal

__device__ inline unsigned short f2bf(float f) {   // round-to-nearest-even
  unsigned u = __float_as_uint(f);
  return (unsigned short)((u + 0x7FFFu + ((u >> 16) & 1u)) >> 16);
}
__device__ inline float4 bf2f4(ushort4 u) {
  float4 r;
  r.x = __uint_as_float((unsigned)u.x << 16);
  r.y = __uint_as_float((unsigned)u.y << 16);
  r.z = __uint_as_float((unsigned)u.z << 16);
  r.w = __uint_as_float((unsigned)u.w << 16);
  return r;
}

// ---------- fused weight prep + sort-counter zeroing: 870 blocks x 256 ----------
__global__ void prep_all(const float* __restrict__ Wq, const float* __restrict__ bq,
                         const float* __restrict__ Wk, const float* __restrict__ bk,
                         const float* __restrict__ Wv, const float* __restrict__ bv,
                         const float* __restrict__ Wo,
                         const float* __restrict__ W_ih, const float* __restrict__ b_ih,
                         const float* __restrict__ W_hh, const float* __restrict__ b_hh,
                         float* __restrict__ WcatQ, float* __restrict__ bcatQ,
                         float* __restrict__ WcatKV, float* __restrict__ bcatKV,
                         float* __restrict__ Wbig, float* __restrict__ WgruCat,
                         float* __restrict__ bgru, int* __restrict__ zint) {
  const int bid = blockIdx.x, j = threadIdx.x;
  if (bid < 129) {                       // Wqk = Wq @ Wk_h^T per head (+ bias row)
    int c0 = bid, h = j >> 7, c = j & 127;
    const float* wkrow = Wk + (size_t)c * 256 + h * 128;
    float acc = 0.f;
    if (c0 < 128) {
      const float* wqrow = Wq + (size_t)c0 * 256 + h * 128;
      for (int d = 0; d < 128; d++) acc += wqrow[d] * wkrow[d];
      WcatQ[c0 * 512 + 256 + j] = acc;
    } else {
      for (int d = 0; d < 128; d++) acc += bq[h * 128 + d] * wkrow[d];
      bcatQ[256 + j] = acc;
    }
  } else if (bid < 257) {                // pack Wq / Wk2 / Wv2 + biases
    int r = bid - 129;
    WcatQ[r * 512 + j] = Wq[r * 256 + j];
    WcatKV[r * 512 + j] = Wk[(size_t)(128 + r) * 256 + j];
    WcatKV[r * 512 + 256 + j] = Wv[(size_t)(128 + r) * 256 + j];
    if (r == 0) {
      bcatQ[j] = bq[j];
      bcatKV[j] = bk[j];
      bcatKV[256 + j] = bv[j];
    }
  } else if (bid < 513) {                // Wbig (2 rows per block)
    int r = (bid - 257) * 2 + (j >> 7), jj = j & 127;
    if (r < 256) {
      int h = r >> 7, c = r & 127;
      float acc = 0.f;
      for (int d = 0; d < 128; d++)
        acc += Wv[(size_t)c * 256 + h * 128 + d] * Wo[(size_t)(h * 128 + d) * 128 + jj];
      Wbig[r * 128 + jj] = acc;
    } else {
      Wbig[r * 128 + jj] = Wo[(size_t)(r - 256) * 128 + jj];
    }
  } else if (bid < 769) {                // WgruCat row r: [x0|msg] -> [rsum|zsum|i_n|h_n]
    int r = bid - 513;
    for (int c = j; c < 512; c += 256) {
      float v;
      if (r < 128) v = (c < 384) ? W_ih[(size_t)r * 384 + c] : 0.f;
      else {
        int rm = r - 128;
        v = (c < 256) ? W_hh[(size_t)rm * 384 + c]
                      : (c < 384 ? 0.f : W_hh[(size_t)rm * 384 + 256 + (c - 384)]);
      }
      WgruCat[(size_t)r * 512 + c] = v;
    }
  } else if (bid == 769) {               // bgru
    bgru[j] = b_ih[j] + b_hh[j];                      // rsum/zsum biases (j<256)
    int c1 = j + 256;
    bgru[c1] = (c1 < 384) ? b_ih[c1] : b_hh[c1 - 128]; // i_n / h_n biases
  } else {                               // bid 770..869: zero cnt+cursor (2N ints)
    int g = ((bid - 770) * 256 + j) * 4;
    if (g < 2 * NN) *reinterpret_cast<int4*>(zint + g) = make_int4(0, 0, 0, 0);
  }
}

// ---------- fused pack: fp32 W[K][Nc] -> bf16 B-fragment layout; 160 blocks ----------
__global__ void pack_all(const float* __restrict__ WcatQ, const float* __restrict__ WcatKV,
                         const float* __restrict__ Wbig, const float* __restrict__ WgruCat,
                         unsigned short* __restrict__ pQ, unsigned short* __restrict__ pKV,
                         unsigned short* __restrict__ pBig, unsigned short* __restrict__ pGRU) {
  const int bid = blockIdx.x;
  const float* W; unsigned short* P; int KK, Nc, base;
  if (bid < 32)      { W = WcatQ;   P = pQ;   KK = 128; Nc = 512; base = 0; }
  else if (bid < 64) { W = WcatKV;  P = pKV;  KK = 128; Nc = 512; base = 32; }
  else if (bid < 96) { W = Wbig;    P = pBig; KK = 512; Nc = 128; base = 64; }
  else               { W = WgruCat; P = pGRU; KK = 256; Nc = 512; base = 96; }
  int idx = (bid - base) * 256 + threadIdx.x;
  int nbs = Nc >> 4;
  int total = (KK >> 5) * nbs * 64;
  if (idx >= total) return;
  int lane = idx & 63;
  int pair = idx >> 6;
  int kb = pair / nbs, nb = pair - kb * nbs;
  int kbase = kb * 32 + (lane >> 4) * 8;
  int col = nb * 16 + (lane & 15);
  unsigned short o[8];
#pragma unroll
  for (int j = 0; j < 8; ++j) o[j] = f2bf(W[(size_t)(kbase + j) * Nc + col]);
  *reinterpret_cast<bf16x8*>(P + (size_t)idx * 8) = *reinterpret_cast<bf16x8*>(o);
}

// ---------- counting sort of edges by dst ----------
__global__ __launch_bounds__(256) void hist_kernel(const int* __restrict__ edges,
                                                   int* __restrict__ cnt) {
  int e = blockIdx.x * 256 + threadIdx.x;
  if (e < EE) atomicAdd(&cnt[edges[EE + e]], 1);
}

// single-kernel exclusive scan: 1024 threads, 49-elem serial strips, two-pass
__global__ __launch_bounds__(1024) void scan_one(const int* __restrict__ cnt,
                                                 int* __restrict__ base) {
  __shared__ int sd[1024];
  const int t = threadIdx.x;
  const int s0 = t * 49;
  const int s1 = min(s0 + 49, NN);
  int sum = 0;
  for (int i = s0; i < s1; ++i) sum += cnt[i];
  sd[t] = sum;
  __syncthreads();
  for (int d = 1; d < 1024; d <<= 1) {
    int add = (t >= d) ? sd[t - d] : 0;
    __syncthreads();
    sd[t] += add;
    __syncthreads();
  }
  int run = (t == 0) ? 0 : sd[t - 1];
  for (int i = s0; i < s1; ++i) { base[i] = run; run += cnt[i]; }
  if (t == 0) base[NN] = EE;
}

__global__ __launch_bounds__(256) void scatter_kernel(const int* __restrict__ edges,
                                                      const int* __restrict__ base,
                                                      int* __restrict__ cursor,
                                                      int2* __restrict__ epairs) {
  int e = blockIdx.x * 256 + threadIdx.x;
  if (e < EE) {
    int s = edges[e];
    int d = edges[EE + e];
    int pos = base[d] + atomicAdd(&cursor[d], 1);
    epairs[pos] = make_int2(e, s);
  }
}

// ---------- MFMA bf16 GEMM; OUT: 0=f32, 1=bf16, 2=both; AF32: A is fp32 ----------
// EMITA: blocks with blockIdx.x==0 also store A-fragments as bf16 to Abf.
template <int OUT, int AF32, int NF, int EMITA>
__global__ __launch_bounds__(256) void gemm_mfma(
    const void* __restrict__ Av, const unsigned short* __restrict__ Wp,
    const float* __restrict__ bias, float* __restrict__ C,
    unsigned short* __restrict__ Cbf, unsigned short* __restrict__ Abf,
    int M, int Arows, int K, int Nc) {
  const int wid = threadIdx.x >> 6, lane = threadIdx.x & 63;
  const int m0 = blockIdx.y * 64 + wid * 16;
  const int nb0 = blockIdx.x * NF;
  const int nbs = Nc >> 4;
  const int row = m0 + (lane & 15);
  const int arow = min(row, Arows - 1);
  const int kq = lane >> 4;
  f32x4 acc[NF];
#pragma unroll
  for (int nf = 0; nf < NF; ++nf) acc[nf] = 0.f;
  const int nkb = K >> 5;
  for (int kb = 0; kb < nkb; ++kb) {
    bf16x8 a;
    if (AF32) {
      const float* ap = (const float*)Av + (size_t)arow * K + kb * 32 + kq * 8;
      const float4 f0 = *(const float4*)ap;
      const float4 f1 = *(const float4*)(ap + 4);
      unsigned short t[8] = {f2bf(f0.x), f2bf(f0.y), f2bf(f0.z), f2bf(f0.w),
                             f2bf(f1.x), f2bf(f1.y), f2bf(f1.z), f2bf(f1.w)};
      a = *reinterpret_cast<bf16x8*>(t);
      if (EMITA) {
        if (blockIdx.x == 0)
          *reinterpret_cast<bf16x8*>(Abf + (size_t)arow * K + kb * 32 + kq * 8) = a;
      }
    } else {
      a = *reinterpret_cast<const bf16x8*>(
          (const unsigned short*)Av + (size_t)arow * K + kb * 32 + kq * 8);
    }
#pragma unroll
    for (int nf = 0; nf < NF; ++nf) {
      bf16x8 b = *reinterpret_cast<const bf16x8*>(
          Wp + ((size_t)(kb * nbs + nb0 + nf) * 64 + lane) * 8);
      acc[nf] = __builtin_amdgcn_mfma_f32_16x16x32_bf16(a, b, acc[nf], 0, 0, 0);
    }
  }
  const int crow0 = m0 + (lane >> 4) * 4;
  const int ccol = lane & 15;
#pragma unroll
  for (int nf = 0; nf < NF; ++nf) {
    const float bv = bias[(nb0 + nf) * 16 + ccol];
#pragma unroll
    for (int r = 0; r < 4; ++r) {
      float v = acc[nf][r] + bv;
      float vp = __shfl_xor(v, 1);
      const int rr = crow0 + r;
      if (rr < M) {
        if (OUT == 0 || OUT == 2)
          C[(size_t)rr * Nc + (nb0 + nf) * 16 + ccol] = v;
        if (OUT >= 1 && !(lane & 1)) {
          ushort2 o;
          o.x = f2bf(v);
          o.y = f2bf(vp);
          *reinterpret_cast<ushort2*>(Cbf + (size_t)rr * Nc +
                                      (nb0 + nf) * 16 + (ccol & ~1)) = o;
        }
      }
    }
  }
}

// ---------- fused attention: one wave per node, half-wave per edge ----------
// 4-edge unrolled main loop (two unpredicated pair-phases), predicated pair tail.
// No max-tracking: logits bounded, exp()/sum(exp()) == reference softmax.
__global__ __launch_bounds__(256) void attn_wave_kernel(
    const float* __restrict__ edge_attr, const unsigned short* __restrict__ QQbf,
    const unsigned short* __restrict__ KVbf, const int* __restrict__ base,
    const int2* __restrict__ epairs, unsigned short* __restrict__ aggbf) {
  const int wid = threadIdx.x >> 6, lane = threadIdx.x & 63;
  const int n = blockIdx.x * 4 + wid;
  if (n >= NN) return;
  const int hh = lane >> 5;            // which edge of the pair
  const int l = lane & 31;             // elem group: 4 elems per 128-block
  const unsigned short* qp = QQbf + (size_t)n * 512 + 4 * l;
  const float4 q0 = bf2f4(*(const ushort4*)(qp));
  const float4 q1 = bf2f4(*(const ushort4*)(qp + 128));
  const float4 w0 = bf2f4(*(const ushort4*)(qp + 256));
  const float4 w1 = bf2f4(*(const ushort4*)(qp + 384));
  const int beg = base[n], end = base[n + 1];
  float s0 = 0.f, s1 = 0.f;
  float4 ae0 = {0.f, 0.f, 0.f, 0.f}, ae1 = {0.f, 0.f, 0.f, 0.f};
  float4 av0 = {0.f, 0.f, 0.f, 0.f}, av1 = {0.f, 0.f, 0.f, 0.f};
  const float SC = 0.08838834764831845f;
  int p = beg;
  const int pend4 = beg + ((end - beg) & ~3);
  for (; p < pend4; p += 4) {
    // issue all 4 edges' loads up front
    const int2 esA = epairs[p + hh];
    const int2 esB = epairs[p + 2 + hh];
    const fv4 eaAv = __builtin_nontemporal_load(
        (const fv4*)(edge_attr + (size_t)esA.x * 128 + 4 * l));
    const fv4 eaBv = __builtin_nontemporal_load(
        (const fv4*)(edge_attr + (size_t)esB.x * 128 + 4 * l));
    const unsigned short* kpA = KVbf + (size_t)esA.y * 512 + 4 * l;
    const unsigned short* kpB = KVbf + (size_t)esB.y * 512 + 4 * l;
    const ushort4 rA0 = *(const ushort4*)(kpA);
    const ushort4 rA1 = *(const ushort4*)(kpA + 128);
    const ushort4 rA2 = *(const ushort4*)(kpA + 256);
    const ushort4 rA3 = *(const ushort4*)(kpA + 384);
    const ushort4 rB0 = *(const ushort4*)(kpB);
    const ushort4 rB1 = *(const ushort4*)(kpB + 128);
    const ushort4 rB2 = *(const ushort4*)(kpB + 256);
    const ushort4 rB3 = *(const ushort4*)(kpB + 384);
    // phase A
    {
      const float4 ea = {eaAv.x, eaAv.y, eaAv.z, eaAv.w};
      const float4 k0 = bf2f4(rA0), k1 = bf2f4(rA1);
      const float4 v0 = bf2f4(rA2), v1 = bf2f4(rA3);
      float p0 = ea.x * w0.x + ea.y * w0.y + ea.z * w0.z + ea.w * w0.w
               + q0.x * k0.x + q0.y * k0.y + q0.z * k0.z + q0.w * k0.w;
      float p1 = ea.x * w1.x + ea.y * w1.y + ea.z * w1.z + ea.w * w1.w
               + q1.x * k1.x + q1.y * k1.y + q1.z * k1.z + q1.w * k1.w;
#pragma unroll
      for (int off = 16; off; off >>= 1) {
        p0 += __shfl_xor(p0, off);
        p1 += __shfl_xor(p1, off);
      }
      float a0 = p0 * SC; a0 = (a0 < 0.f) ? 0.2f * a0 : a0;
      float a1 = p1 * SC; a1 = (a1 < 0.f) ? 0.2f * a1 : a1;
      const float x0 = __expf(a0), x1 = __expf(a1);
      s0 += x0; s1 += x1;
      ae0.x += x0 * ea.x; ae0.y += x0 * ea.y; ae0.z += x0 * ea.z; ae0.w += x0 * ea.w;
      ae1.x += x1 * ea.x; ae1.y += x1 * ea.y; ae1.z += x1 * ea.z; ae1.w += x1 * ea.w;
      av0.x += x0 * v0.x; av0.y += x0 * v0.y; av0.z += x0 * v0.z; av0.w += x0 * v0.w;
      av1.x += x1 * v1.x; av1.y += x1 * v1.y; av1.z += x1 * v1.z; av1.w += x1 * v1.w;
    }
    // phase B
    {
      const float4 ea = {eaBv.x, eaBv.y, eaBv.z, eaBv.w};
      const float4 k0 = bf2f4(rB0), k1 = bf2f4(rB1);
      const float4 v0 = bf2f4(rB2), v1 = bf2f4(rB3);
      float p0 = ea.x * w0.x + ea.y * w0.y + ea.z * w0.z + ea.w * w0.w
               + q0.x * k0.x + q0.y * k0.y + q0.z * k0.z + q0.w * k0.w;
      float p1 = ea.x * w1.x + ea.y * w1.y + ea.z * w1.z + ea.w * w1.w
               + q1.x * k1.x + q1.y * k1.y + q1.z * k1.z + q1.w * k1.w;
#pragma unroll
      for (int off = 16; off; off >>= 1) {
        p0 += __shfl_xor(p0, off);
        p1 += __shfl_xor(p1, off);
      }
      float a0 = p0 * SC; a0 = (a0 < 0.f) ? 0.2f * a0 : a0;
      float a1 = p1 * SC; a1 = (a1 < 0.f) ? 0.2f * a1 : a1;
      const float x0 = __expf(a0), x1 = __expf(a1);
      s0 += x0; s1 += x1;
      ae0.x += x0 * ea.x; ae0.y += x0 * ea.y; ae0.z += x0 * ea.z; ae0.w += x0 * ea.w;
      ae1.x += x1 * ea.x; ae1.y += x1 * ea.y; ae1.z += x1 * ea.z; ae1.w += x1 * ea.w;
      av0.x += x0 * v0.x; av0.y += x0 * v0.y; av0.z += x0 * v0.z; av0.w += x0 * v0.w;
      av1.x += x1 * v1.x; av1.y += x1 * v1.y; av1.z += x1 * v1.z; av1.w += x1 * v1.w;
    }
  }
  // tail: predicated pair loop (<=2 iterations)
  for (; p < end; p += 2) {
    const int pe = min(p + hh, end - 1);
    const bool act = (p + hh < end);
    const int2 es = epairs[pe];
    const fv4 eav = __builtin_nontemporal_load(
        (const fv4*)(edge_attr + (size_t)es.x * 128 + 4 * l));
    const float4 ea = {eav.x, eav.y, eav.z, eav.w};
    const unsigned short* kp = KVbf + (size_t)es.y * 512 + 4 * l;
    const float4 k0 = bf2f4(*(const ushort4*)(kp));
    const float4 k1 = bf2f4(*(const ushort4*)(kp + 128));
    const float4 v0 = bf2f4(*(const ushort4*)(kp + 256));
    const float4 v1 = bf2f4(*(const ushort4*)(kp + 384));
    float p0 = ea.x * w0.x + ea.y * w0.y + ea.z * w0.z + ea.w * w0.w
             + q0.x * k0.x + q0.y * k0.y + q0.z * k0.z + q0.w * k0.w;
    float p1 = ea.x * w1.x + ea.y * w1.y + ea.z * w1.z + ea.w * w1.w
             + q1.x * k1.x + q1.y * k1.y + q1.z * k1.z + q1.w * k1.w;
#pragma unroll
    for (int off = 16; off; off >>= 1) {
      p0 += __shfl_xor(p0, off);
      p1 += __shfl_xor(p1, off);
    }
    float a0 = p0 * SC; a0 = (a0 < 0.f) ? 0.2f * a0 : a0;
    float a1 = p1 * SC; a1 = (a1 < 0.f) ? 0.2f * a1 : a1;
    const float x0 = act ? __expf(a0) : 0.f;
    const float x1 = act ? __expf(a1) : 0.f;
    s0 += x0; s1 += x1;
    ae0.x += x0 * ea.x; ae0.y += x0 * ea.y; ae0.z += x0 * ea.z; ae0.w += x0 * ea.w;
    ae1.x += x1 * ea.x; ae1.y += x1 * ea.y; ae1.z += x1 * ea.z; ae1.w += x1 * ea.w;
    av0.x += x0 * v0.x; av0.y += x0 * v0.y; av0.z += x0 * v0.z; av0.w += x0 * v0.w;
    av1.x += x1 * v1.x; av1.y += x1 * v1.y; av1.z += x1 * v1.z; av1.w += x1 * v1.w;
  }
  // combine the two half-wave accumulators
  s0 += __shfl_xor(s0, 32); s1 += __shfl_xor(s1, 32);
  ae0.x += __shfl_xor(ae0.x, 32); ae0.y += __shfl_xor(ae0.y, 32);
  ae0.z += __shfl_xor(ae0.z, 32); ae0.w += __shfl_xor(ae0.w, 32);
  ae1.x += __shfl_xor(ae1.x, 32); ae1.y += __shfl_xor(ae1.y, 32);
  ae1.z += __shfl_xor(ae1.z, 32); ae1.w += __shfl_xor(ae1.w, 32);
  av0.x += __shfl_xor(av0.x, 32); av0.y += __shfl_xor(av0.y, 32);
  av0.z += __shfl_xor(av0.z, 32); av0.w += __shfl_xor(av0.w, 32);
  av1.x += __shfl_xor(av1.x, 32); av1.y += __shfl_xor(av1.y, 32);
  av1.z += __shfl_xor(av1.z, 32); av1.w += __shfl_xor(av1.w, 32);
  const float i0 = 1.f / (s0 + 1e-16f), i1 = 1.f / (s1 + 1e-16f);
  if (hh == 0) {
    unsigned short* op = aggbf + (size_t)n * 512 + 4 * l;
    ushort4 o;
    o.x = f2bf(ae0.x * i0); o.y = f2bf(ae0.y * i0);
    o.z = f2bf(ae0.z * i0); o.w = f2bf(ae0.w * i0);
    *(ushort4*)op = o;
    o.x = f2bf(ae1.x * i1); o.y = f2bf(ae1.y * i1);
    o.z = f2bf(ae1.z * i1); o.w = f2bf(ae1.w * i1);
    *(ushort4*)(op + 128) = o;
    o.x = f2bf(av0.x * i0); o.y = f2bf(av0.y * i0);
    o.z = f2bf(av0.z * i0); o.w = f2bf(av0.w * i0);
    *(ushort4*)(op + 256) = o;
    o.x = f2bf(av1.x * i1); o.y = f2bf(av1.y * i1);
    o.z = f2bf(av1.z * i1); o.w = f2bf(av1.w * i1);
    *(ushort4*)(op + 384) = o;
  }
}

// ---------- fused GRU: [x0|msg] @ WgruCat -> gates -> out, one GEMM ----------
// grid (4, MPAD/64); block: 64 rows x 32 out-dims (4 gate groups x 2 frags)
__global__ __launch_bounds__(256) void gru_fused(
    const unsigned short* __restrict__ x0bf, const unsigned short* __restrict__ msgbf,
    const unsigned short* __restrict__ pGRU, const float* __restrict__ bgru,
    const float* __restrict__ msgf, float* __restrict__ out) {
  const int wid = threadIdx.x >> 6, lane = threadIdx.x & 63;
  const int m0 = blockIdx.y * 64 + wid * 16;
  const int xq = blockIdx.x;           // output-dim quarter: d in [xq*32, xq*32+32)
  const int row = m0 + (lane & 15);
  const int ar = min(row, NN - 1);
  const int kq = lane >> 4;
  f32x4 acc[4][2];
#pragma unroll
  for (int g = 0; g < 4; ++g)
#pragma unroll
    for (int f = 0; f < 2; ++f) acc[g][f] = 0.f;
  for (int kb = 0; kb < 8; ++kb) {
    bf16x8 a;
    if (kb < 4) {
      a = *reinterpret_cast<const bf16x8*>(x0bf + (size_t)ar * 128 +
                                           kb * 32 + kq * 8);
    } else {
      a = *reinterpret_cast<const bf16x8*>(msgbf + (size_t)ar * 128 +
                                           (kb - 4) * 32 + kq * 8);
    }
#pragma unroll
    for (int g = 0; g < 4; ++g)
#pragma unroll
      for (int f = 0; f < 2; ++f) {
        const int nf = g * 8 + xq * 2 + f;
        bf16x8 b = *reinterpret_cast<const bf16x8*>(
            pGRU + ((size_t)(kb * 32 + nf) * 64 + lane) * 8);
        acc[g][f] = __builtin_amdgcn_mfma_f32_16x16x32_bf16(a, b, acc[g][f], 0, 0, 0);
      }
  }
  const int crow0 = m0 + (lane >> 4) * 4;
  const int ccol = lane & 15;
#pragma unroll
  for (int f = 0; f < 2; ++f) {
    const int d = xq * 32 + f * 16 + ccol;
    const float brs = bgru[d], bzs = bgru[128 + d];
    const float bin = bgru[256 + d], bhn = bgru[384 + d];
#pragma unroll
    for (int r = 0; r < 4; ++r) {
      const int rr = crow0 + r;
      if (rr < NN) {
        const float rs = acc[0][f][r] + brs;
        const float zs = acc[1][f][r] + bzs;
        const float iv = acc[2][f][r] + bin;
        const float hv = acc[3][f][r] + bhn;
        const float rg = 1.f / (1.f + __expf(-rs));
        const float zg = 1.f / (1.f + __expf(-zs));
        const float ng = tanhf(iv + rg * hv);
        const float h = msgf[(size_t)rr * 128 + d];
        out[(size_t)rr * 128 + d] = (1.f - zg) * ng + zg * h;
      }
    }
  }
}

extern "C" void kernel_launch(void* const* d_in, const int* in_sizes, int n_in,
                              void* d_out, int out_size, void* d_ws, size_t ws_size,
                              hipStream_t stream) {
  const float* x0 = (const float*)d_in[0];
  const float* x1 = (const float*)d_in[1];
  const float* edge_attr = (const float*)d_in[2];
  const int* edges = (const int*)d_in[3];
  const float* Wq = (const float*)d_in[5];
  const float* bq = (const float*)d_in[6];
  const float* Wk = (const float*)d_in[7];
  const float* bk = (const float*)d_in[8];
  const float* Wv = (const float*)d_in[9];
  const float* bv = (const float*)d_in[10];
  const float* Wo = (const float*)d_in[11];
  const float* bo = (const float*)d_in[12];
  const float* W_ih = (const float*)d_in[13];
  const float* b_ih = (const float*)d_in[14];
  const float* W_hh = (const float*)d_in[15];
  const float* b_hh = (const float*)d_in[16];
  float* out = (float*)d_out;
  float* wsf = (float*)d_ws;

  unsigned short* QQbf  = (unsigned short*)(wsf + OFF_QQBF);
  unsigned short* KVbf  = (unsigned short*)(wsf + OFF_KVBF);
  unsigned short* aggbf = (unsigned short*)(wsf + OFF_AGGBF);
  float* msgf  = wsf + OFF_MSGF;
  unsigned short* msgbf = (unsigned short*)(wsf + OFF_MSGBF);
  unsigned short* x0bf  = (unsigned short*)(wsf + OFF_X0BF);
  int* ip    = (int*)(wsf + OFF_INT);
  int* cntb  = ip;                       // N
  int* curb  = ip + NN;                  // N
  int* baseb = ip + 2 * NN;              // N+1 (+1 pad -> int2 align)
  int2* epairs = (int2*)(ip + 3 * NN + 2);   // 2E ints, 8B aligned
  float* WcatQ  = wsf + OFF_WCATQ;
  float* WcatKV = wsf + OFF_WCATKV;
  float* Wbigb  = wsf + OFF_WBIG;
  float* WgruC  = wsf + OFF_WGRU;
  float* bcatQ  = wsf + OFF_BCATQ;
  float* bcatKV = wsf + OFF_BCATKV;
  float* bgru   = wsf + OFF_BGRU;
  unsigned short* pQ   = (unsigned short*)(wsf + OFF_PQ);
  unsigned short* pKV  = (unsigned short*)(wsf + OFF_PKV);
  unsigned short* pBig = (unsigned short*)(wsf + OFF_PBIG);
  unsigned short* pGRU = (unsigned short*)(wsf + OFF_PGRU);

  // --- weight prep + zero sort counters (no memset nodes in the graph) ---
  prep_all<<<870, 256, 0, stream>>>(Wq, bq, Wk, bk, Wv, bv, Wo, W_ih, b_ih,
                                    W_hh, b_hh, WcatQ, bcatQ, WcatKV, bcatKV,
                                    Wbigb, WgruC, bgru, ip);
  pack_all<<<160, 256, 0, stream>>>(WcatQ, WcatKV, Wbigb, WgruC, pQ, pKV, pBig, pGRU);

  // --- counting sort of edges by dst ---
  hist_kernel<<<EE / 256, 256, 0, stream>>>(edges, cntb);
  scan_one<<<1, 1024, 0, stream>>>(cntb, baseb);
  scatter_kernel<<<EE / 256, 256, 0, stream>>>(edges, baseb, curb, epairs);

  // --- node projections (fp32 A on the fly -> bf16 out); QQ also emits x0bf ---
  dim3 blk(256);
  gemm_mfma<1, 1, 8, 1><<<dim3(4, MPAD / 64), blk, 0, stream>>>(
      x0, pQ, bcatQ, nullptr, QQbf, x0bf, NN, NN, 128, 512);
  gemm_mfma<1, 1, 8, 0><<<dim3(4, MPAD / 64), blk, 0, stream>>>(
      x1, pKV, bcatKV, nullptr, KVbf, nullptr, NN, NN, 128, 512);

  // --- fused attention (one wave per node) ---
  attn_wave_kernel<<<(NN + 3) / 4, 256, 0, stream>>>(edge_attr, QQbf, KVbf,
                                                     baseb, epairs, aggbf);

  // --- msg = aggbf @ pBig + bo (fp32 + bf16) ---
  gemm_mfma<2, 0, 4, 0><<<dim3(2, MPAD / 64), blk, 0, stream>>>(
      aggbf, pBig, bo, msgf, msgbf, nullptr, NN, NN, 512, 128);

  // --- GRU: one fused GEMM + gates -> out ---
  gru_fused<<<dim3(4, MPAD / 64), blk, 0, stream>>>(x0bf, msgbf, pGRU, bgru, msgf, out);
}

// Round 9
// 549.604 us; speedup vs baseline: 1.0004x; 1.0004x over previous
//
#include <hip/hip_runtime.h>
#include <hip/hip_bf16.h>
#include <math.h>

#define NN 50000
#define EE 800000
#define MPAD 50048          // 64-aligned row pad for MFMA GEMMs

// ---------- workspace layout (offsets in floats) ----------
#define OFF_QQBF   0ull          // MPAD*512 bf16 = 12,812,288 fl
#define OFF_KVBF   12900000ull   // MPAD*512 bf16
#define OFF_AGGBF  25900000ull   // MPAD*512 bf16
#define OFF_MSGF   38800000ull   // MPAD*128 fp32 = 6,406,144 fl
#define OFF_MSGBF  45300000ull   // MPAD*128 bf16 = 3,203,072 fl
#define OFF_INT    48600000ull   // ints: 3N+2+2E = 1,750,002
#define OFF_WCATQ  50500000ull   // 128*512 fp32
#define OFF_WCATKV 50600000ull
#define OFF_WBIG   50700000ull   // 512*128 fp32
#define OFF_WGRU   50800000ull   // 256*512 fp32
#define OFF_BCATQ  51000000ull   // 512
#define OFF_BCATKV 51001000ull   // 512
#define OFF_BGRU   51002000ull   // 512
#define OFF_PQ     51010000ull   // packed bf16
#define OFF_PKV    51050000ull
#define OFF_PBIG   51090000ull
#define OFF_PGRU   51130000ull   // 131072 shorts
#define OFF_X0BF   51200000ull   // MPAD*128 bf16 = 3,203,072 fl
// end ~54.41M floats = 218 MB

typedef short bf16x8 __attribute__((ext_vector_type(8)));
typedef float f32x4 __attribute__((ext_vector_type(4)));
typedef float fv4 __attribute__((ext_vector_type(4)));    // native vec for nontemporal

__device__ inline unsigned short f2bf(float f) {   // round-to-nearest-even
  unsigned u = __float_as_uint(f);
  return (unsigned short)((u + 0x7FFFu + ((u >> 16) & 1u)) >> 16);
}
__device__ inline float4 bf2f4(ushort4 u) {
  float4 r;
  r.x = __uint_as_float((unsigned)u.x << 16);
  r.y = __uint_as_float((unsigned)u.y << 16);
  r.z = __uint_as_float((unsigned)u.z << 16);
  r.w = __uint_as_float((unsigned)u.w << 16);
  return r;
}

// ---------- fused weight prep + sort-counter zeroing: 870 blocks x 256 ----------
__global__ void prep_all(const float* __restrict__ Wq, const float* __restrict__ bq,
                         const float* __restrict__ Wk, const float* __restrict__ bk,
                         const float* __restrict__ Wv, const float* __restrict__ bv,
                         const float* __restrict__ Wo,
                         const float* __restrict__ W_ih, const float* __restrict__ b_ih,
                         const float* __restrict__ W_hh, const float* __restrict__ b_hh,
                         float* __restrict__ WcatQ, float* __restrict__ bcatQ,
                         float* __restrict__ WcatKV, float* __restrict__ bcatKV,
                         float* __restrict__ Wbig, float* __restrict__ WgruCat,
                         float* __restrict__ bgru, int* __restrict__ zint) {
  const int bid = blockIdx.x, j = threadIdx.x;
  if (bid < 129) {                       // Wqk = Wq @ Wk_h^T per head (+ bias row)
    int c0 = bid, h = j >> 7, c = j & 127;
    const float* wkrow = Wk + (size_t)c * 256 + h * 128;
    float acc = 0.f;
    if (c0 < 128) {
      const float* wqrow = Wq + (size_t)c0 * 256 + h * 128;
      for (int d = 0; d < 128; d++) acc += wqrow[d] * wkrow[d];
      WcatQ[c0 * 512 + 256 + j] = acc;
    } else {
      for (int d = 0; d < 128; d++) acc += bq[h * 128 + d] * wkrow[d];
      bcatQ[256 + j] = acc;
    }
  } else if (bid < 257) {                // pack Wq / Wk2 / Wv2 + biases
    int r = bid - 129;
    WcatQ[r * 512 + j] = Wq[r * 256 + j];
    WcatKV[r * 512 + j] = Wk[(size_t)(128 + r) * 256 + j];
    WcatKV[r * 512 + 256 + j] = Wv[(size_t)(128 + r) * 256 + j];
    if (r == 0) {
      bcatQ[j] = bq[j];
      bcatKV[j] = bk[j];
      bcatKV[256 + j] = bv[j];
    }
  } else if (bid < 513) {                // Wbig (2 rows per block)
    int r = (bid - 257) * 2 + (j >> 7), jj = j & 127;
    if (r < 256) {
      int h = r >> 7, c = r & 127;
      float acc = 0.f;
      for (int d = 0; d < 128; d++)
        acc += Wv[(size_t)c * 256 + h * 128 + d] * Wo[(size_t)(h * 128 + d) * 128 + jj];
      Wbig[r * 128 + jj] = acc;
    } else {
      Wbig[r * 128 + jj] = Wo[(size_t)(r - 256) * 128 + jj];
    }
  } else if (bid < 769) {                // WgruCat row r: [x0|msg] -> [rsum|zsum|i_n|h_n]
    int r = bid - 513;
    for (int c = j; c < 512; c += 256) {
      float v;
      if (r < 128) v = (c < 384) ? W_ih[(size_t)r * 384 + c] : 0.f;
      else {
        int rm = r - 128;
        v = (c < 256) ? W_hh[(size_t)rm * 384 + c]
                      : (c < 384 ? 0.f : W_hh[(size_t)rm * 384 + 256 + (c - 384)]);
      }
      WgruCat[(size_t)r * 512 + c] = v;
    }
  } else if (bid == 769) {               // bgru
    bgru[j] = b_ih[j] + b_hh[j];                      // rsum/zsum biases (j<256)
    int c1 = j + 256;
    bgru[c1] = (c1 < 384) ? b_ih[c1] : b_hh[c1 - 128]; // i_n / h_n biases
  } else {                               // bid 770..869: zero cnt+cursor (2N ints)
    int g = ((bid - 770) * 256 + j) * 4;
    if (g < 2 * NN) *reinterpret_cast<int4*>(zint + g) = make_int4(0, 0, 0, 0);
  }
}

// ---------- fused pack: fp32 W[K][Nc] -> bf16 B-fragment layout; 160 blocks ----------
__global__ void pack_all(const float* __restrict__ WcatQ, const float* __restrict__ WcatKV,
                         const float* __restrict__ Wbig, const float* __restrict__ WgruCat,
                         unsigned short* __restrict__ pQ, unsigned short* __restrict__ pKV,
                         unsigned short* __restrict__ pBig, unsigned short* __restrict__ pGRU) {
  const int bid = blockIdx.x;
  const float* W; unsigned short* P; int KK, Nc, base;
  if (bid < 32)      { W = WcatQ;   P = pQ;   KK = 128; Nc = 512; base = 0; }
  else if (bid < 64) { W = WcatKV;  P = pKV;  KK = 128; Nc = 512; base = 32; }
  else if (bid < 96) { W = Wbig;    P = pBig; KK = 512; Nc = 128; base = 64; }
  else               { W = WgruCat; P = pGRU; KK = 256; Nc = 512; base = 96; }
  int idx = (bid - base) * 256 + threadIdx.x;
  int nbs = Nc >> 4;
  int total = (KK >> 5) * nbs * 64;
  if (idx >= total) return;
  int lane = idx & 63;
  int pair = idx >> 6;
  int kb = pair / nbs, nb = pair - kb * nbs;
  int kbase = kb * 32 + (lane >> 4) * 8;
  int col = nb * 16 + (lane & 15);
  unsigned short o[8];
#pragma unroll
  for (int j = 0; j < 8; ++j) o[j] = f2bf(W[(size_t)(kbase + j) * Nc + col]);
  *reinterpret_cast<bf16x8*>(P + (size_t)idx * 8) = *reinterpret_cast<bf16x8*>(o);
}

// ---------- counting sort of edges by dst ----------
__global__ __launch_bounds__(256) void hist_kernel(const int* __restrict__ edges,
                                                   int* __restrict__ cnt) {
  int e = blockIdx.x * 256 + threadIdx.x;
  if (e < EE) atomicAdd(&cnt[edges[EE + e]], 1);
}

// single-kernel exclusive scan: 1024 threads, 49-elem serial strips, two-pass
__global__ __launch_bounds__(1024) void scan_one(const int* __restrict__ cnt,
                                                 int* __restrict__ base) {
  __shared__ int sd[1024];
  const int t = threadIdx.x;
  const int s0 = t * 49;
  const int s1 = min(s0 + 49, NN);
  int sum = 0;
  for (int i = s0; i < s1; ++i) sum += cnt[i];
  sd[t] = sum;
  __syncthreads();
  for (int d = 1; d < 1024; d <<= 1) {
    int add = (t >= d) ? sd[t - d] : 0;
    __syncthreads();
    sd[t] += add;
    __syncthreads();
  }
  int run = (t == 0) ? 0 : sd[t - 1];
  for (int i = s0; i < s1; ++i) { base[i] = run; run += cnt[i]; }
  if (t == 0) base[NN] = EE;
}

__global__ __launch_bounds__(256) void scatter_kernel(const int* __restrict__ edges,
                                                      const int* __restrict__ base,
                                                      int* __restrict__ cursor,
                                                      int2* __restrict__ epairs) {
  int e = blockIdx.x * 256 + threadIdx.x;
  if (e < EE) {
    int s = edges[e];
    int d = edges[EE + e];
    int pos = base[d] + atomicAdd(&cursor[d], 1);
    epairs[pos] = make_int2(e, s);
  }
}

// ---------- MFMA bf16 GEMM; OUT: 0=f32, 1=bf16, 2=both; AF32: A is fp32 ----------
// EMITA: blocks with blockIdx.x==0 also store A-fragments as bf16 to Abf.
template <int OUT, int AF32, int NF, int EMITA>
__global__ __launch_bounds__(256) void gemm_mfma(
    const void* __restrict__ Av, const unsigned short* __restrict__ Wp,
    const float* __restrict__ bias, float* __restrict__ C,
    unsigned short* __restrict__ Cbf, unsigned short* __restrict__ Abf,
    int M, int Arows, int K, int Nc) {
  const int wid = threadIdx.x >> 6, lane = threadIdx.x & 63;
  const int m0 = blockIdx.y * 64 + wid * 16;
  const int nb0 = blockIdx.x * NF;
  const int nbs = Nc >> 4;
  const int row = m0 + (lane & 15);
  const int arow = min(row, Arows - 1);
  const int kq = lane >> 4;
  f32x4 acc[NF];
#pragma unroll
  for (int nf = 0; nf < NF; ++nf) acc[nf] = 0.f;
  const int nkb = K >> 5;
  for (int kb = 0; kb < nkb; ++kb) {
    bf16x8 a;
    if (AF32) {
      const float* ap = (const float*)Av + (size_t)arow * K + kb * 32 + kq * 8;
      const float4 f0 = *(const float4*)ap;
      const float4 f1 = *(const float4*)(ap + 4);
      unsigned short t[8] = {f2bf(f0.x), f2bf(f0.y), f2bf(f0.z), f2bf(f0.w),
                             f2bf(f1.x), f2bf(f1.y), f2bf(f1.z), f2bf(f1.w)};
      a = *reinterpret_cast<bf16x8*>(t);
      if (EMITA) {
        if (blockIdx.x == 0)
          *reinterpret_cast<bf16x8*>(Abf + (size_t)arow * K + kb * 32 + kq * 8) = a;
      }
    } else {
      a = *reinterpret_cast<const bf16x8*>(
          (const unsigned short*)Av + (size_t)arow * K + kb * 32 + kq * 8);
    }
#pragma unroll
    for (int nf = 0; nf < NF; ++nf) {
      bf16x8 b = *reinterpret_cast<const bf16x8*>(
          Wp + ((size_t)(kb * nbs + nb0 + nf) * 64 + lane) * 8);
      acc[nf] = __builtin_amdgcn_mfma_f32_16x16x32_bf16(a, b, acc[nf], 0, 0, 0);
    }
  }
  const int crow0 = m0 + (lane >> 4) * 4;
  const int ccol = lane & 15;
#pragma unroll
  for (int nf = 0; nf < NF; ++nf) {
    const float bv = bias[(nb0 + nf) * 16 + ccol];
#pragma unroll
    for (int r = 0; r < 4; ++r) {
      float v = acc[nf][r] + bv;
      float vp = __shfl_xor(v, 1);
      const int rr = crow0 + r;
      if (rr < M) {
        if (OUT == 0 || OUT == 2)
          C[(size_t)rr * Nc + (nb0 + nf) * 16 + ccol] = v;
        if (OUT >= 1 && !(lane & 1)) {
          ushort2 o;
          o.x = f2bf(v);
          o.y = f2bf(vp);
          *reinterpret_cast<ushort2*>(Cbf + (size_t)rr * Nc +
                                      (nb0 + nf) * 16 + (ccol & ~1)) = o;
        }
      }
    }
  }
}

// ---------- fused attention: one wave per node, half-wave per edge ----------
// (r7 2-edge loop: r8's 4-edge unroll regressed — TLP already hides latency)
__global__ __launch_bounds__(256) void attn_wave_kernel(
    const float* __restrict__ edge_attr, const unsigned short* __restrict__ QQbf,
    const unsigned short* __restrict__ KVbf, const int* __restrict__ base,
    const int2* __restrict__ epairs, unsigned short* __restrict__ aggbf) {
  const int wid = threadIdx.x >> 6, lane = threadIdx.x & 63;
  const int n = blockIdx.x * 4 + wid;
  if (n >= NN) return;
  const int hh = lane >> 5;            // which edge of the pair
  const int l = lane & 31;             // elem group: 4 elems per 128-block
  const unsigned short* qp = QQbf + (size_t)n * 512 + 4 * l;
  const float4 q0 = bf2f4(*(const ushort4*)(qp));
  const float4 q1 = bf2f4(*(const ushort4*)(qp + 128));
  const float4 w0 = bf2f4(*(const ushort4*)(qp + 256));
  const float4 w1 = bf2f4(*(const ushort4*)(qp + 384));
  const int beg = base[n], end = base[n + 1];
  float s0 = 0.f, s1 = 0.f;
  float4 ae0 = {0.f, 0.f, 0.f, 0.f}, ae1 = {0.f, 0.f, 0.f, 0.f};
  float4 av0 = {0.f, 0.f, 0.f, 0.f}, av1 = {0.f, 0.f, 0.f, 0.f};
  const float SC = 0.08838834764831845f;
  for (int p = beg; p < end; p += 2) {
    const int pe = min(p + hh, end - 1);
    const bool act = (p + hh < end);
    const int2 es = epairs[pe];
    const fv4 eav = __builtin_nontemporal_load(
        (const fv4*)(edge_attr + (size_t)es.x * 128 + 4 * l));
    const float4 ea = {eav.x, eav.y, eav.z, eav.w};
    const unsigned short* kp = KVbf + (size_t)es.y * 512 + 4 * l;
    const float4 k0 = bf2f4(*(const ushort4*)(kp));
    const float4 k1 = bf2f4(*(const ushort4*)(kp + 128));
    const float4 v0 = bf2f4(*(const ushort4*)(kp + 256));
    const float4 v1 = bf2f4(*(const ushort4*)(kp + 384));
    float p0 = ea.x * w0.x + ea.y * w0.y + ea.z * w0.z + ea.w * w0.w
             + q0.x * k0.x + q0.y * k0.y + q0.z * k0.z + q0.w * k0.w;
    float p1 = ea.x * w1.x + ea.y * w1.y + ea.z * w1.z + ea.w * w1.w
             + q1.x * k1.x + q1.y * k1.y + q1.z * k1.z + q1.w * k1.w;
#pragma unroll
    for (int off = 16; off; off >>= 1) {
      p0 += __shfl_xor(p0, off);
      p1 += __shfl_xor(p1, off);
    }
    float a0 = p0 * SC; a0 = (a0 < 0.f) ? 0.2f * a0 : a0;
    float a1 = p1 * SC; a1 = (a1 < 0.f) ? 0.2f * a1 : a1;
    const float x0 = act ? __expf(a0) : 0.f;
    const float x1 = act ? __expf(a1) : 0.f;
    s0 += x0; s1 += x1;
    ae0.x += x0 * ea.x; ae0.y += x0 * ea.y; ae0.z += x0 * ea.z; ae0.w += x0 * ea.w;
    ae1.x += x1 * ea.x; ae1.y += x1 * ea.y; ae1.z += x1 * ea.z; ae1.w += x1 * ea.w;
    av0.x += x0 * v0.x; av0.y += x0 * v0.y; av0.z += x0 * v0.z; av0.w += x0 * v0.w;
    av1.x += x1 * v1.x; av1.y += x1 * v1.y; av1.z += x1 * v1.z; av1.w += x1 * v1.w;
  }
  // combine the two half-wave accumulators
  s0 += __shfl_xor(s0, 32); s1 += __shfl_xor(s1, 32);
  ae0.x += __shfl_xor(ae0.x, 32); ae0.y += __shfl_xor(ae0.y, 32);
  ae0.z += __shfl_xor(ae0.z, 32); ae0.w += __shfl_xor(ae0.w, 32);
  ae1.x += __shfl_xor(ae1.x, 32); ae1.y += __shfl_xor(ae1.y, 32);
  ae1.z += __shfl_xor(ae1.z, 32); ae1.w += __shfl_xor(ae1.w, 32);
  av0.x += __shfl_xor(av0.x, 32); av0.y += __shfl_xor(av0.y, 32);
  av0.z += __shfl_xor(av0.z, 32); av0.w += __shfl_xor(av0.w, 32);
  av1.x += __shfl_xor(av1.x, 32); av1.y += __shfl_xor(av1.y, 32);
  av1.z += __shfl_xor(av1.z, 32); av1.w += __shfl_xor(av1.w, 32);
  const float i0 = 1.f / (s0 + 1e-16f), i1 = 1.f / (s1 + 1e-16f);
  if (hh == 0) {
    unsigned short* op = aggbf + (size_t)n * 512 + 4 * l;
    ushort4 o;
    o.x = f2bf(ae0.x * i0); o.y = f2bf(ae0.y * i0);
    o.z = f2bf(ae0.z * i0); o.w = f2bf(ae0.w * i0);
    *(ushort4*)op = o;
    o.x = f2bf(ae1.x * i1); o.y = f2bf(ae1.y * i1);
    o.z = f2bf(ae1.z * i1); o.w = f2bf(ae1.w * i1);
    *(ushort4*)(op + 128) = o;
    o.x = f2bf(av0.x * i0); o.y = f2bf(av0.y * i0);
    o.z = f2bf(av0.z * i0); o.w = f2bf(av0.w * i0);
    *(ushort4*)(op + 256) = o;
    o.x = f2bf(av1.x * i1); o.y = f2bf(av1.y * i1);
    o.z = f2bf(av1.z * i1); o.w = f2bf(av1.w * i1);
    *(ushort4*)(op + 384) = o;
  }
}

// ---------- fused GRU: [x0|msg] @ WgruCat -> gates -> out, one GEMM ----------
// grid (4, MPAD/64); block: 64 rows x 32 out-dims (4 gate groups x 2 frags)
__global__ __launch_bounds__(256) void gru_fused(
    const unsigned short* __restrict__ x0bf, const unsigned short* __restrict__ msgbf,
    const unsigned short* __restrict__ pGRU, const float* __restrict__ bgru,
    const float* __restrict__ msgf, float* __restrict__ out) {
  const int wid = threadIdx.x >> 6, lane = threadIdx.x & 63;
  const int m0 = blockIdx.y * 64 + wid * 16;
  const int xq = blockIdx.x;           // output-dim quarter: d in [xq*32, xq*32+32)
  const int row = m0 + (lane & 15);
  const int ar = min(row, NN - 1);
  const int kq = lane >> 4;
  f32x4 acc[4][2];
#pragma unroll
  for (int g = 0; g < 4; ++g)
#pragma unroll
    for (int f = 0; f < 2; ++f) acc[g][f] = 0.f;
  for (int kb = 0; kb < 8; ++kb) {
    bf16x8 a;
    if (kb < 4) {
      a = *reinterpret_cast<const bf16x8*>(x0bf + (size_t)ar * 128 +
                                           kb * 32 + kq * 8);
    } else {
      a = *reinterpret_cast<const bf16x8*>(msgbf + (size_t)ar * 128 +
                                           (kb - 4) * 32 + kq * 8);
    }
#pragma unroll
    for (int g = 0; g < 4; ++g)
#pragma unroll
      for (int f = 0; f < 2; ++f) {
        const int nf = g * 8 + xq * 2 + f;
        bf16x8 b = *reinterpret_cast<const bf16x8*>(
            pGRU + ((size_t)(kb * 32 + nf) * 64 + lane) * 8);
        acc[g][f] = __builtin_amdgcn_mfma_f32_16x16x32_bf16(a, b, acc[g][f], 0, 0, 0);
      }
  }
  const int crow0 = m0 + (lane >> 4) * 4;
  const int ccol = lane & 15;
#pragma unroll
  for (int f = 0; f < 2; ++f) {
    const int d = xq * 32 + f * 16 + ccol;
    const float brs = bgru[d], bzs = bgru[128 + d];
    const float bin = bgru[256 + d], bhn = bgru[384 + d];
#pragma unroll
    for (int r = 0; r < 4; ++r) {
      const int rr = crow0 + r;
      if (rr < NN) {
        const float rs = acc[0][f][r] + brs;
        const float zs = acc[1][f][r] + bzs;
        const float iv = acc[2][f][r] + bin;
        const float hv = acc[3][f][r] + bhn;
        const float rg = 1.f / (1.f + __expf(-rs));
        const float zg = 1.f / (1.f + __expf(-zs));
        const float ng = tanhf(iv + rg * hv);
        const float h = msgf[(size_t)rr * 128 + d];
        out[(size_t)rr * 128 + d] = (1.f - zg) * ng + zg * h;
      }
    }
  }
}

extern "C" void kernel_launch(void* const* d_in, const int* in_sizes, int n_in,
                              void* d_out, int out_size, void* d_ws, size_t ws_size,
                              hipStream_t stream) {
  const float* x0 = (const float*)d_in[0];
  const float* x1 = (const float*)d_in[1];
  const float* edge_attr = (const float*)d_in[2];
  const int* edges = (const int*)d_in[3];
  const float* Wq = (const float*)d_in[5];
  const float* bq = (const float*)d_in[6];
  const float* Wk = (const float*)d_in[7];
  const float* bk = (const float*)d_in[8];
  const float* Wv = (const float*)d_in[9];
  const float* bv = (const float*)d_in[10];
  const float* Wo = (const float*)d_in[11];
  const float* bo = (const float*)d_in[12];
  const float* W_ih = (const float*)d_in[13];
  const float* b_ih = (const float*)d_in[14];
  const float* W_hh = (const float*)d_in[15];
  const float* b_hh = (const float*)d_in[16];
  float* out = (float*)d_out;
  float* wsf = (float*)d_ws;

  unsigned short* QQbf  = (unsigned short*)(wsf + OFF_QQBF);
  unsigned short* KVbf  = (unsigned short*)(wsf + OFF_KVBF);
  unsigned short* aggbf = (unsigned short*)(wsf + OFF_AGGBF);
  float* msgf  = wsf + OFF_MSGF;
  unsigned short* msgbf = (unsigned short*)(wsf + OFF_MSGBF);
  unsigned short* x0bf  = (unsigned short*)(wsf + OFF_X0BF);
  int* ip    = (int*)(wsf + OFF_INT);
  int* cntb  = ip;                       // N
  int* curb  = ip + NN;                  // N
  int* baseb = ip + 2 * NN;              // N+1 (+1 pad -> int2 align)
  int2* epairs = (int2*)(ip + 3 * NN + 2);   // 2E ints, 8B aligned
  float* WcatQ  = wsf + OFF_WCATQ;
  float* WcatKV = wsf + OFF_WCATKV;
  float* Wbigb  = wsf + OFF_WBIG;
  float* WgruC  = wsf + OFF_WGRU;
  float* bcatQ  = wsf + OFF_BCATQ;
  float* bcatKV = wsf + OFF_BCATKV;
  float* bgru   = wsf + OFF_BGRU;
  unsigned short* pQ   = (unsigned short*)(wsf + OFF_PQ);
  unsigned short* pKV  = (unsigned short*)(wsf + OFF_PKV);
  unsigned short* pBig = (unsigned short*)(wsf + OFF_PBIG);
  unsigned short* pGRU = (unsigned short*)(wsf + OFF_PGRU);

  // --- weight prep + zero sort counters (no memset nodes in the graph) ---
  prep_all<<<870, 256, 0, stream>>>(Wq, bq, Wk, bk, Wv, bv, Wo, W_ih, b_ih,
                                    W_hh, b_hh, WcatQ, bcatQ, WcatKV, bcatKV,
                                    Wbigb, WgruC, bgru, ip);
  pack_all<<<160, 256, 0, stream>>>(WcatQ, WcatKV, Wbigb, WgruC, pQ, pKV, pBig, pGRU);

  // --- counting sort of edges by dst ---
  hist_kernel<<<EE / 256, 256, 0, stream>>>(edges, cntb);
  scan_one<<<1, 1024, 0, stream>>>(cntb, baseb);
  scatter_kernel<<<EE / 256, 256, 0, stream>>>(edges, baseb, curb, epairs);

  // --- node projections (fp32 A on the fly -> bf16 out); QQ also emits x0bf ---
  dim3 blk(256);
  gemm_mfma<1, 1, 8, 1><<<dim3(4, MPAD / 64), blk, 0, stream>>>(
      x0, pQ, bcatQ, nullptr, QQbf, x0bf, NN, NN, 128, 512);
  gemm_mfma<1, 1, 8, 0><<<dim3(4, MPAD / 64), blk, 0, stream>>>(
      x1, pKV, bcatKV, nullptr, KVbf, nullptr, NN, NN, 128, 512);

  // --- fused attention (one wave per node) ---
  attn_wave_kernel<<<(NN + 3) / 4, 256, 0, stream>>>(edge_attr, QQbf, KVbf,
                                                     baseb, epairs, aggbf);

  // --- msg = aggbf @ pBig + bo (fp32 + bf16) ---
  gemm_mfma<2, 0, 4, 0><<<dim3(2, MPAD / 64), blk, 0, stream>>>(
      aggbf, pBig, bo, msgf, msgbf, nullptr, NN, NN, 512, 128);

  // --- GRU: one fused GEMM + gates -> out ---
  gru_fused<<<dim3(4, MPAD / 64), blk, 0, stream>>>(x0bf, msgbf, pGRU, bgru, msgf, out);
}

// Round 10
// 477.717 us; speedup vs baseline: 1.1510x; 1.1505x over previous
//
#include <hip/hip_runtime.h>
#include <hip/hip_bf16.h>
#include <math.h>

#define NN 50000
#define EE 800000
#define MPAD 50048          // 64-aligned row pad for MFMA GEMMs

// ---------- workspace layout (offsets in floats) ----------
#define OFF_QQBF   0ull          // MPAD*512 bf16 = 12,812,288 fl
#define OFF_KVBF   12900000ull   // MPAD*512 bf16
#define OFF_AGGBF  25900000ull   // MPAD*512 bf16
#define OFF_MSGF   38800000ull   // MPAD*128 fp32 = 6,406,144 fl
#define OFF_MSGBF  45300000ull   // MPAD*128 bf16 = 3,203,072 fl
#define OFF_INT    48600000ull   // ints: 4N+130+2E = 1,800,130
#define OFF_WCATQ  50500000ull   // 128*512 fp32
#define OFF_WCATKV 50600000ull
#define OFF_WBIG   50700000ull   // 512*128 fp32
#define OFF_WGRU   50800000ull   // 256*512 fp32
#define OFF_BCATQ  51000000ull   // 512
#define OFF_BCATKV 51001000ull   // 512
#define OFF_BGRU   51002000ull   // 512
#define OFF_PQ     51010000ull   // packed bf16
#define OFF_PKV    51050000ull
#define OFF_PBIG   51090000ull
#define OFF_PGRU   51130000ull   // 131072 shorts
#define OFF_X0BF   51200000ull   // MPAD*128 bf16 = 3,203,072 fl
// end ~54.41M floats = 218 MB

typedef short bf16x8 __attribute__((ext_vector_type(8)));
typedef float f32x4 __attribute__((ext_vector_type(4)));
typedef float fv4 __attribute__((ext_vector_type(4)));    // native vec for nontemporal

__device__ inline unsigned short f2bf(float f) {   // round-to-nearest-even
  unsigned u = __float_as_uint(f);
  return (unsigned short)((u + 0x7FFFu + ((u >> 16) & 1u)) >> 16);
}
__device__ inline float4 bf2f4(ushort4 u) {
  float4 r;
  r.x = __uint_as_float((unsigned)u.x << 16);
  r.y = __uint_as_float((unsigned)u.y << 16);
  r.z = __uint_as_float((unsigned)u.z << 16);
  r.w = __uint_as_float((unsigned)u.w << 16);
  return r;
}

// ---------- fused weight prep + sort-counter zeroing: 870 blocks x 256 ----------
__global__ void prep_all(const float* __restrict__ Wq, const float* __restrict__ bq,
                         const float* __restrict__ Wk, const float* __restrict__ bk,
                         const float* __restrict__ Wv, const float* __restrict__ bv,
                         const float* __restrict__ Wo,
                         const float* __restrict__ W_ih, const float* __restrict__ b_ih,
                         const float* __restrict__ W_hh, const float* __restrict__ b_hh,
                         float* __restrict__ WcatQ, float* __restrict__ bcatQ,
                         float* __restrict__ WcatKV, float* __restrict__ bcatKV,
                         float* __restrict__ Wbig, float* __restrict__ WgruCat,
                         float* __restrict__ bgru, int* __restrict__ zint) {
  const int bid = blockIdx.x, j = threadIdx.x;
  if (bid < 129) {                       // Wqk = Wq @ Wk_h^T per head (+ bias row)
    int c0 = bid, h = j >> 7, c = j & 127;
    const float* wkrow = Wk + (size_t)c * 256 + h * 128;
    float acc = 0.f;
    if (c0 < 128) {
      const float* wqrow = Wq + (size_t)c0 * 256 + h * 128;
      for (int d = 0; d < 128; d++) acc += wqrow[d] * wkrow[d];
      WcatQ[c0 * 512 + 256 + j] = acc;
    } else {
      for (int d = 0; d < 128; d++) acc += bq[h * 128 + d] * wkrow[d];
      bcatQ[256 + j] = acc;
    }
  } else if (bid < 257) {                // pack Wq / Wk2 / Wv2 + biases
    int r = bid - 129;
    WcatQ[r * 512 + j] = Wq[r * 256 + j];
    WcatKV[r * 512 + j] = Wk[(size_t)(128 + r) * 256 + j];
    WcatKV[r * 512 + 256 + j] = Wv[(size_t)(128 + r) * 256 + j];
    if (r == 0) {
      bcatQ[j] = bq[j];
      bcatKV[j] = bk[j];
      bcatKV[256 + j] = bv[j];
    }
  } else if (bid < 513) {                // Wbig (2 rows per block)
    int r = (bid - 257) * 2 + (j >> 7), jj = j & 127;
    if (r < 256) {
      int h = r >> 7, c = r & 127;
      float acc = 0.f;
      for (int d = 0; d < 128; d++)
        acc += Wv[(size_t)c * 256 + h * 128 + d] * Wo[(size_t)(h * 128 + d) * 128 + jj];
      Wbig[r * 128 + jj] = acc;
    } else {
      Wbig[r * 128 + jj] = Wo[(size_t)(r - 256) * 128 + jj];
    }
  } else if (bid < 769) {                // WgruCat row r: [x0|msg] -> [rsum|zsum|i_n|h_n]
    int r = bid - 513;
    for (int c = j; c < 512; c += 256) {
      float v;
      if (r < 128) v = (c < 384) ? W_ih[(size_t)r * 384 + c] : 0.f;
      else {
        int rm = r - 128;
        v = (c < 256) ? W_hh[(size_t)rm * 384 + c]
                      : (c < 384 ? 0.f : W_hh[(size_t)rm * 384 + 256 + (c - 384)]);
      }
      WgruCat[(size_t)r * 512 + c] = v;
    }
  } else if (bid == 769) {               // bgru
    bgru[j] = b_ih[j] + b_hh[j];                      // rsum/zsum biases (j<256)
    int c1 = j + 256;
    bgru[c1] = (c1 < 384) ? b_ih[c1] : b_hh[c1 - 128]; // i_n / h_n biases
  } else {                               // bid 770..869: zero cnt+cursor (2N ints)
    int g = ((bid - 770) * 256 + j) * 4;
    if (g < 2 * NN) *reinterpret_cast<int4*>(zint + g) = make_int4(0, 0, 0, 0);
  }
}

// ---------- fused pack: fp32 W[K][Nc] -> bf16 B-fragment layout; 160 blocks ----------
__global__ void pack_all(const float* __restrict__ WcatQ, const float* __restrict__ WcatKV,
                         const float* __restrict__ Wbig, const float* __restrict__ WgruCat,
                         unsigned short* __restrict__ pQ, unsigned short* __restrict__ pKV,
                         unsigned short* __restrict__ pBig, unsigned short* __restrict__ pGRU) {
  const int bid = blockIdx.x;
  const float* W; unsigned short* P; int KK, Nc, base;
  if (bid < 32)      { W = WcatQ;   P = pQ;   KK = 128; Nc = 512; base = 0; }
  else if (bid < 64) { W = WcatKV;  P = pKV;  KK = 128; Nc = 512; base = 32; }
  else if (bid < 96) { W = Wbig;    P = pBig; KK = 512; Nc = 128; base = 64; }
  else               { W = WgruCat; P = pGRU; KK = 256; Nc = 512; base = 96; }
  int idx = (bid - base) * 256 + threadIdx.x;
  int nbs = Nc >> 4;
  int total = (KK >> 5) * nbs * 64;
  if (idx >= total) return;
  int lane = idx & 63;
  int pair = idx >> 6;
  int kb = pair / nbs, nb = pair - kb * nbs;
  int kbase = kb * 32 + (lane >> 4) * 8;
  int col = nb * 16 + (lane & 15);
  unsigned short o[8];
#pragma unroll
  for (int j = 0; j < 8; ++j) o[j] = f2bf(W[(size_t)(kbase + j) * Nc + col]);
  *reinterpret_cast<bf16x8*>(P + (size_t)idx * 8) = *reinterpret_cast<bf16x8*>(o);
}

// ---------- counting sort of edges by dst (3-kernel coalesced scan) ----------
__global__ __launch_bounds__(256) void hist_kernel(const int* __restrict__ edges,
                                                   int* __restrict__ cnt) {
  int e = blockIdx.x * 256 + threadIdx.x;
  if (e < EE) atomicAdd(&cnt[edges[EE + e]], 1);
}

__global__ __launch_bounds__(1024) void scan_partial(const int* __restrict__ cnt,
                                                     int* __restrict__ basep,
                                                     int* __restrict__ bsum) {
  __shared__ int sd[1024];
  int t = threadIdx.x, g = blockIdx.x * 1024 + t;
  int v = (g < NN) ? cnt[g] : 0;
  sd[t] = v;
  __syncthreads();
  for (int d = 1; d < 1024; d <<= 1) {
    int add = (t >= d) ? sd[t - d] : 0;
    __syncthreads();
    sd[t] += add;
    __syncthreads();
  }
  if (g < NN) basep[g] = sd[t] - v;
  if (t == 1023) bsum[blockIdx.x] = sd[1023];
}

__global__ void scan_bsum(const int* __restrict__ bsum, int* __restrict__ boff,
                          int* __restrict__ baseNN, int nblk) {
  int l = threadIdx.x;
  int v = (l < nblk) ? bsum[l] : 0;
  int incl = v;
#pragma unroll
  for (int off = 1; off < 64; off <<= 1) {
    int o = __shfl_up(incl, off);
    if (l >= off) incl += o;
  }
  if (l < nblk) boff[l] = incl - v;
  if (l == 63) baseNN[0] = incl;
}

__global__ __launch_bounds__(1024) void scan_add(const int* __restrict__ basep,
                                                 const int* __restrict__ boff,
                                                 int* __restrict__ base) {
  int g = blockIdx.x * 1024 + threadIdx.x;
  if (g < NN) base[g] = basep[g] + boff[blockIdx.x];
}

__global__ __launch_bounds__(256) void scatter_kernel(const int* __restrict__ edges,
                                                      const int* __restrict__ base,
                                                      int* __restrict__ cursor,
                                                      int2* __restrict__ epairs) {
  int e = blockIdx.x * 256 + threadIdx.x;
  if (e < EE) {
    int s = edges[e];
    int d = edges[EE + e];
    int pos = base[d] + atomicAdd(&cursor[d], 1);
    epairs[pos] = make_int2(e, s);
  }
}

// ---------- MFMA bf16 GEMM; OUT: 0=f32, 1=bf16, 2=both; AF32: A is fp32 ----------
// EMITA: blocks with blockIdx.x==0 also store A-fragments as bf16 to Abf.
template <int OUT, int AF32, int NF, int EMITA>
__global__ __launch_bounds__(256) void gemm_mfma(
    const void* __restrict__ Av, const unsigned short* __restrict__ Wp,
    const float* __restrict__ bias, float* __restrict__ C,
    unsigned short* __restrict__ Cbf, unsigned short* __restrict__ Abf,
    int M, int Arows, int K, int Nc) {
  const int wid = threadIdx.x >> 6, lane = threadIdx.x & 63;
  const int m0 = blockIdx.y * 64 + wid * 16;
  const int nb0 = blockIdx.x * NF;
  const int nbs = Nc >> 4;
  const int row = m0 + (lane & 15);
  const int arow = min(row, Arows - 1);
  const int kq = lane >> 4;
  f32x4 acc[NF];
#pragma unroll
  for (int nf = 0; nf < NF; ++nf) acc[nf] = 0.f;
  const int nkb = K >> 5;
  for (int kb = 0; kb < nkb; ++kb) {
    bf16x8 a;
    if (AF32) {
      const float* ap = (const float*)Av + (size_t)arow * K + kb * 32 + kq * 8;
      const float4 f0 = *(const float4*)ap;
      const float4 f1 = *(const float4*)(ap + 4);
      unsigned short t[8] = {f2bf(f0.x), f2bf(f0.y), f2bf(f0.z), f2bf(f0.w),
                             f2bf(f1.x), f2bf(f1.y), f2bf(f1.z), f2bf(f1.w)};
      a = *reinterpret_cast<bf16x8*>(t);
      if (EMITA) {
        if (blockIdx.x == 0)
          *reinterpret_cast<bf16x8*>(Abf + (size_t)arow * K + kb * 32 + kq * 8) = a;
      }
    } else {
      a = *reinterpret_cast<const bf16x8*>(
          (const unsigned short*)Av + (size_t)arow * K + kb * 32 + kq * 8);
    }
#pragma unroll
    for (int nf = 0; nf < NF; ++nf) {
      bf16x8 b = *reinterpret_cast<const bf16x8*>(
          Wp + ((size_t)(kb * nbs + nb0 + nf) * 64 + lane) * 8);
      acc[nf] = __builtin_amdgcn_mfma_f32_16x16x32_bf16(a, b, acc[nf], 0, 0, 0);
    }
  }
  const int crow0 = m0 + (lane >> 4) * 4;
  const int ccol = lane & 15;
#pragma unroll
  for (int nf = 0; nf < NF; ++nf) {
    const float bv = bias[(nb0 + nf) * 16 + ccol];
#pragma unroll
    for (int r = 0; r < 4; ++r) {
      float v = acc[nf][r] + bv;
      float vp = __shfl_xor(v, 1);
      const int rr = crow0 + r;
      if (rr < M) {
        if (OUT == 0 || OUT == 2)
          C[(size_t)rr * Nc + (nb0 + nf) * 16 + ccol] = v;
        if (OUT >= 1 && !(lane & 1)) {
          ushort2 o;
          o.x = f2bf(v);
          o.y = f2bf(vp);
          *reinterpret_cast<ushort2*>(Cbf + (size_t)rr * Nc +
                                      (nb0 + nf) * 16 + (ccol & ~1)) = o;
        }
      }
    }
  }
}

// ---------- fused attention: one wave per node, half-wave per edge ----------
// (2-edge loop; 4-edge unroll measured neutral in r8/r9)
__global__ __launch_bounds__(256) void attn_wave_kernel(
    const float* __restrict__ edge_attr, const unsigned short* __restrict__ QQbf,
    const unsigned short* __restrict__ KVbf, const int* __restrict__ base,
    const int2* __restrict__ epairs, unsigned short* __restrict__ aggbf) {
  const int wid = threadIdx.x >> 6, lane = threadIdx.x & 63;
  const int n = blockIdx.x * 4 + wid;
  if (n >= NN) return;
  const int hh = lane >> 5;            // which edge of the pair
  const int l = lane & 31;             // elem group: 4 elems per 128-block
  const unsigned short* qp = QQbf + (size_t)n * 512 + 4 * l;
  const float4 q0 = bf2f4(*(const ushort4*)(qp));
  const float4 q1 = bf2f4(*(const ushort4*)(qp + 128));
  const float4 w0 = bf2f4(*(const ushort4*)(qp + 256));
  const float4 w1 = bf2f4(*(const ushort4*)(qp + 384));
  const int beg = base[n], end = base[n + 1];
  float s0 = 0.f, s1 = 0.f;
  float4 ae0 = {0.f, 0.f, 0.f, 0.f}, ae1 = {0.f, 0.f, 0.f, 0.f};
  float4 av0 = {0.f, 0.f, 0.f, 0.f}, av1 = {0.f, 0.f, 0.f, 0.f};
  const float SC = 0.08838834764831845f;
  for (int p = beg; p < end; p += 2) {
    const int pe = min(p + hh, end - 1);
    const bool act = (p + hh < end);
    const int2 es = epairs[pe];
    const fv4 eav = __builtin_nontemporal_load(
        (const fv4*)(edge_attr + (size_t)es.x * 128 + 4 * l));
    const float4 ea = {eav.x, eav.y, eav.z, eav.w};
    const unsigned short* kp = KVbf + (size_t)es.y * 512 + 4 * l;
    const float4 k0 = bf2f4(*(const ushort4*)(kp));
    const float4 k1 = bf2f4(*(const ushort4*)(kp + 128));
    const float4 v0 = bf2f4(*(const ushort4*)(kp + 256));
    const float4 v1 = bf2f4(*(const ushort4*)(kp + 384));
    float p0 = ea.x * w0.x + ea.y * w0.y + ea.z * w0.z + ea.w * w0.w
             + q0.x * k0.x + q0.y * k0.y + q0.z * k0.z + q0.w * k0.w;
    float p1 = ea.x * w1.x + ea.y * w1.y + ea.z * w1.z + ea.w * w1.w
             + q1.x * k1.x + q1.y * k1.y + q1.z * k1.z + q1.w * k1.w;
#pragma unroll
    for (int off = 16; off; off >>= 1) {
      p0 += __shfl_xor(p0, off);
      p1 += __shfl_xor(p1, off);
    }
    float a0 = p0 * SC; a0 = (a0 < 0.f) ? 0.2f * a0 : a0;
    float a1 = p1 * SC; a1 = (a1 < 0.f) ? 0.2f * a1 : a1;
    const float x0 = act ? __expf(a0) : 0.f;
    const float x1 = act ? __expf(a1) : 0.f;
    s0 += x0; s1 += x1;
    ae0.x += x0 * ea.x; ae0.y += x0 * ea.y; ae0.z += x0 * ea.z; ae0.w += x0 * ea.w;
    ae1.x += x1 * ea.x; ae1.y += x1 * ea.y; ae1.z += x1 * ea.z; ae1.w += x1 * ea.w;
    av0.x += x0 * v0.x; av0.y += x0 * v0.y; av0.z += x0 * v0.z; av0.w += x0 * v0.w;
    av1.x += x1 * v1.x; av1.y += x1 * v1.y; av1.z += x1 * v1.z; av1.w += x1 * v1.w;
  }
  // combine the two half-wave accumulators
  s0 += __shfl_xor(s0, 32); s1 += __shfl_xor(s1, 32);
  ae0.x += __shfl_xor(ae0.x, 32); ae0.y += __shfl_xor(ae0.y, 32);
  ae0.z += __shfl_xor(ae0.z, 32); ae0.w += __shfl_xor(ae0.w, 32);
  ae1.x += __shfl_xor(ae1.x, 32); ae1.y += __shfl_xor(ae1.y, 32);
  ae1.z += __shfl_xor(ae1.z, 32); ae1.w += __shfl_xor(ae1.w, 32);
  av0.x += __shfl_xor(av0.x, 32); av0.y += __shfl_xor(av0.y, 32);
  av0.z += __shfl_xor(av0.z, 32); av0.w += __shfl_xor(av0.w, 32);
  av1.x += __shfl_xor(av1.x, 32); av1.y += __shfl_xor(av1.y, 32);
  av1.z += __shfl_xor(av1.z, 32); av1.w += __shfl_xor(av1.w, 32);
  const float i0 = 1.f / (s0 + 1e-16f), i1 = 1.f / (s1 + 1e-16f);
  if (hh == 0) {
    unsigned short* op = aggbf + (size_t)n * 512 + 4 * l;
    ushort4 o;
    o.x = f2bf(ae0.x * i0); o.y = f2bf(ae0.y * i0);
    o.z = f2bf(ae0.z * i0); o.w = f2bf(ae0.w * i0);
    *(ushort4*)op = o;
    o.x = f2bf(ae1.x * i1); o.y = f2bf(ae1.y * i1);
    o.z = f2bf(ae1.z * i1); o.w = f2bf(ae1.w * i1);
    *(ushort4*)(op + 128) = o;
    o.x = f2bf(av0.x * i0); o.y = f2bf(av0.y * i0);
    o.z = f2bf(av0.z * i0); o.w = f2bf(av0.w * i0);
    *(ushort4*)(op + 256) = o;
    o.x = f2bf(av1.x * i1); o.y = f2bf(av1.y * i1);
    o.z = f2bf(av1.z * i1); o.w = f2bf(av1.w * i1);
    *(ushort4*)(op + 384) = o;
  }
}

// ---------- fused GRU: [x0|msg] @ WgruCat -> gates -> out, one GEMM ----------
// grid (4, MPAD/64); block: 64 rows x 32 out-dims (4 gate groups x 2 frags)
__global__ __launch_bounds__(256) void gru_fused(
    const unsigned short* __restrict__ x0bf, const unsigned short* __restrict__ msgbf,
    const unsigned short* __restrict__ pGRU, const float* __restrict__ bgru,
    const float* __restrict__ msgf, float* __restrict__ out) {
  const int wid = threadIdx.x >> 6, lane = threadIdx.x & 63;
  const int m0 = blockIdx.y * 64 + wid * 16;
  const int xq = blockIdx.x;           // output-dim quarter: d in [xq*32, xq*32+32)
  const int row = m0 + (lane & 15);
  const int ar = min(row, NN - 1);
  const int kq = lane >> 4;
  f32x4 acc[4][2];
#pragma unroll
  for (int g = 0; g < 4; ++g)
#pragma unroll
    for (int f = 0; f < 2; ++f) acc[g][f] = 0.f;
  for (int kb = 0; kb < 8; ++kb) {
    bf16x8 a;
    if (kb < 4) {
      a = *reinterpret_cast<const bf16x8*>(x0bf + (size_t)ar * 128 +
                                           kb * 32 + kq * 8);
    } else {
      a = *reinterpret_cast<const bf16x8*>(msgbf + (size_t)ar * 128 +
                                           (kb - 4) * 32 + kq * 8);
    }
#pragma unroll
    for (int g = 0; g < 4; ++g)
#pragma unroll
      for (int f = 0; f < 2; ++f) {
        const int nf = g * 8 + xq * 2 + f;
        bf16x8 b = *reinterpret_cast<const bf16x8*>(
            pGRU + ((size_t)(kb * 32 + nf) * 64 + lane) * 8);
        acc[g][f] = __builtin_amdgcn_mfma_f32_16x16x32_bf16(a, b, acc[g][f], 0, 0, 0);
      }
  }
  const int crow0 = m0 + (lane >> 4) * 4;
  const int ccol = lane & 15;
#pragma unroll
  for (int f = 0; f < 2; ++f) {
    const int d = xq * 32 + f * 16 + ccol;
    const float brs = bgru[d], bzs = bgru[128 + d];
    const float bin = bgru[256 + d], bhn = bgru[384 + d];
#pragma unroll
    for (int r = 0; r < 4; ++r) {
      const int rr = crow0 + r;
      if (rr < NN) {
        const float rs = acc[0][f][r] + brs;
        const float zs = acc[1][f][r] + bzs;
        const float iv = acc[2][f][r] + bin;
        const float hv = acc[3][f][r] + bhn;
        const float rg = 1.f / (1.f + __expf(-rs));
        const float zg = 1.f / (1.f + __expf(-zs));
        const float ng = tanhf(iv + rg * hv);
        const float h = msgf[(size_t)rr * 128 + d];
        out[(size_t)rr * 128 + d] = (1.f - zg) * ng + zg * h;
      }
    }
  }
}

extern "C" void kernel_launch(void* const* d_in, const int* in_sizes, int n_in,
                              void* d_out, int out_size, void* d_ws, size_t ws_size,
                              hipStream_t stream) {
  const float* x0 = (const float*)d_in[0];
  const float* x1 = (const float*)d_in[1];
  const float* edge_attr = (const float*)d_in[2];
  const int* edges = (const int*)d_in[3];
  const float* Wq = (const float*)d_in[5];
  const float* bq = (const float*)d_in[6];
  const float* Wk = (const float*)d_in[7];
  const float* bk = (const float*)d_in[8];
  const float* Wv = (const float*)d_in[9];
  const float* bv = (const float*)d_in[10];
  const float* Wo = (const float*)d_in[11];
  const float* bo = (const float*)d_in[12];
  const float* W_ih = (const float*)d_in[13];
  const float* b_ih = (const float*)d_in[14];
  const float* W_hh = (const float*)d_in[15];
  const float* b_hh = (const float*)d_in[16];
  float* out = (float*)d_out;
  float* wsf = (float*)d_ws;

  unsigned short* QQbf  = (unsigned short*)(wsf + OFF_QQBF);
  unsigned short* KVbf  = (unsigned short*)(wsf + OFF_KVBF);
  unsigned short* aggbf = (unsigned short*)(wsf + OFF_AGGBF);
  float* msgf  = wsf + OFF_MSGF;
  unsigned short* msgbf = (unsigned short*)(wsf + OFF_MSGBF);
  unsigned short* x0bf  = (unsigned short*)(wsf + OFF_X0BF);
  int* ip    = (int*)(wsf + OFF_INT);
  int* cntb  = ip;                       // N
  int* curb  = ip + NN;                  // N
  int* bpart = ip + 2 * NN;              // N
  int* baseb = ip + 3 * NN;              // N+1
  int* bsumb = ip + 4 * NN + 1;          // 64
  int* boffb = ip + 4 * NN + 65;         // 64 (+1 pad for int2 align)
  int2* epairs = (int2*)(ip + 4 * NN + 130);   // 2E ints, 8B aligned
  float* WcatQ  = wsf + OFF_WCATQ;
  float* WcatKV = wsf + OFF_WCATKV;
  float* Wbigb  = wsf + OFF_WBIG;
  float* WgruC  = wsf + OFF_WGRU;
  float* bcatQ  = wsf + OFF_BCATQ;
  float* bcatKV = wsf + OFF_BCATKV;
  float* bgru   = wsf + OFF_BGRU;
  unsigned short* pQ   = (unsigned short*)(wsf + OFF_PQ);
  unsigned short* pKV  = (unsigned short*)(wsf + OFF_PKV);
  unsigned short* pBig = (unsigned short*)(wsf + OFF_PBIG);
  unsigned short* pGRU = (unsigned short*)(wsf + OFF_PGRU);

  // --- weight prep + zero sort counters (no memset nodes in the graph) ---
  prep_all<<<870, 256, 0, stream>>>(Wq, bq, Wk, bk, Wv, bv, Wo, W_ih, b_ih,
                                    W_hh, b_hh, WcatQ, bcatQ, WcatKV, bcatKV,
                                    Wbigb, WgruC, bgru, ip);
  pack_all<<<160, 256, 0, stream>>>(WcatQ, WcatKV, Wbigb, WgruC, pQ, pKV, pBig, pGRU);

  // --- counting sort of edges by dst (coalesced two-level scan) ---
  hist_kernel<<<EE / 256, 256, 0, stream>>>(edges, cntb);
  const int nblk = (NN + 1023) / 1024;   // 49
  scan_partial<<<nblk, 1024, 0, stream>>>(cntb, bpart, bsumb);
  scan_bsum<<<1, 64, 0, stream>>>(bsumb, boffb, baseb + NN, nblk);
  scan_add<<<nblk, 1024, 0, stream>>>(bpart, boffb, baseb);
  scatter_kernel<<<EE / 256, 256, 0, stream>>>(edges, baseb, curb, epairs);

  // --- node projections (fp32 A on the fly -> bf16 out); QQ also emits x0bf ---
  dim3 blk(256);
  gemm_mfma<1, 1, 8, 1><<<dim3(4, MPAD / 64), blk, 0, stream>>>(
      x0, pQ, bcatQ, nullptr, QQbf, x0bf, NN, NN, 128, 512);
  gemm_mfma<1, 1, 8, 0><<<dim3(4, MPAD / 64), blk, 0, stream>>>(
      x1, pKV, bcatKV, nullptr, KVbf, nullptr, NN, NN, 128, 512);

  // --- fused attention (one wave per node) ---
  attn_wave_kernel<<<(NN + 3) / 4, 256, 0, stream>>>(edge_attr, QQbf, KVbf,
                                                     baseb, epairs, aggbf);

  // --- msg = aggbf @ pBig + bo (fp32 + bf16) ---
  gemm_mfma<2, 0, 4, 0><<<dim3(2, MPAD / 64), blk, 0, stream>>>(
      aggbf, pBig, bo, msgf, msgbf, nullptr, NN, NN, 512, 128);

  // --- GRU: one fused GEMM + gates -> out ---
  gru_fused<<<dim3(4, MPAD / 64), blk, 0, stream>>>(x0bf, msgbf, pGRU, bgru, msgf, out);
}

// Round 11
// 436.615 us; speedup vs baseline: 1.2593x; 1.0941x over previous
//
#include <hip/hip_runtime.h>
#include <hip/hip_bf16.h>
#include <math.h>

#define NN 50000
#define EE 800000
#define MPAD 50048          // 64-aligned row pad for MFMA GEMMs

// ---------- workspace layout (offsets in floats) ----------
#define OFF_QQBF   0ull          // MPAD*512 bf16 = 12,812,288 fl
#define OFF_KVBF   12900000ull   // MPAD*512 bf16
#define OFF_AGGBF  25900000ull   // MPAD*512 bf16
#define OFF_MSGBF  45300000ull   // MPAD*128 bf16 = 3,203,072 fl
#define OFF_INT    48600000ull   // ints: 4N+130+2E = 1,800,130
#define OFF_WCATQ  50500000ull   // 128*512 fp32
#define OFF_WCATKV 50600000ull
#define OFF_WBIG   50700000ull   // 512*128 fp32
#define OFF_WGRU   50800000ull   // 256*512 fp32
#define OFF_BCATQ  51000000ull   // 512
#define OFF_BCATKV 51001000ull   // 512
#define OFF_BGRU   51002000ull   // 512
#define OFF_PQ     51010000ull   // packed bf16
#define OFF_PKV    51050000ull
#define OFF_PBIG   51090000ull
#define OFF_PGRU   51130000ull   // 131072 shorts
#define OFF_X0BF   51200000ull   // MPAD*128 bf16 = 3,203,072 fl
// end ~54.41M floats = 218 MB

typedef short bf16x8 __attribute__((ext_vector_type(8)));
typedef float f32x4 __attribute__((ext_vector_type(4)));
typedef float fv4 __attribute__((ext_vector_type(4)));    // native vec for nontemporal

__device__ inline unsigned short f2bf(float f) {   // round-to-nearest-even
  unsigned u = __float_as_uint(f);
  return (unsigned short)((u + 0x7FFFu + ((u >> 16) & 1u)) >> 16);
}
__device__ inline float4 bf2f4(ushort4 u) {
  float4 r;
  r.x = __uint_as_float((unsigned)u.x << 16);
  r.y = __uint_as_float((unsigned)u.y << 16);
  r.z = __uint_as_float((unsigned)u.z << 16);
  r.w = __uint_as_float((unsigned)u.w << 16);
  return r;
}

// ---------- K1: weight prep + sort-counter zeroing: 870 blocks x 256 ----------
__global__ void prep_all(const float* __restrict__ Wq, const float* __restrict__ bq,
                         const float* __restrict__ Wk, const float* __restrict__ bk,
                         const float* __restrict__ Wv, const float* __restrict__ bv,
                         const float* __restrict__ Wo,
                         const float* __restrict__ W_ih, const float* __restrict__ b_ih,
                         const float* __restrict__ W_hh, const float* __restrict__ b_hh,
                         float* __restrict__ WcatQ, float* __restrict__ bcatQ,
                         float* __restrict__ WcatKV, float* __restrict__ bcatKV,
                         float* __restrict__ Wbig, float* __restrict__ WgruCat,
                         float* __restrict__ bgru, int* __restrict__ zint) {
  const int bid = blockIdx.x, j = threadIdx.x;
  if (bid < 129) {                       // Wqk = Wq @ Wk_h^T per head (+ bias row)
    int c0 = bid, h = j >> 7, c = j & 127;
    const float* wkrow = Wk + (size_t)c * 256 + h * 128;
    float acc = 0.f;
    if (c0 < 128) {
      const float* wqrow = Wq + (size_t)c0 * 256 + h * 128;
      for (int d = 0; d < 128; d++) acc += wqrow[d] * wkrow[d];
      WcatQ[c0 * 512 + 256 + j] = acc;
    } else {
      for (int d = 0; d < 128; d++) acc += bq[h * 128 + d] * wkrow[d];
      bcatQ[256 + j] = acc;
    }
  } else if (bid < 257) {                // pack Wq / Wk2 / Wv2 + biases
    int r = bid - 129;
    WcatQ[r * 512 + j] = Wq[r * 256 + j];
    WcatKV[r * 512 + j] = Wk[(size_t)(128 + r) * 256 + j];
    WcatKV[r * 512 + 256 + j] = Wv[(size_t)(128 + r) * 256 + j];
    if (r == 0) {
      bcatQ[j] = bq[j];
      bcatKV[j] = bk[j];
      bcatKV[256 + j] = bv[j];
    }
  } else if (bid < 513) {                // Wbig (2 rows per block)
    int r = (bid - 257) * 2 + (j >> 7), jj = j & 127;
    if (r < 256) {
      int h = r >> 7, c = r & 127;
      float acc = 0.f;
      for (int d = 0; d < 128; d++)
        acc += Wv[(size_t)c * 256 + h * 128 + d] * Wo[(size_t)(h * 128 + d) * 128 + jj];
      Wbig[r * 128 + jj] = acc;
    } else {
      Wbig[r * 128 + jj] = Wo[(size_t)(r - 256) * 128 + jj];
    }
  } else if (bid < 769) {                // WgruCat row r: [x0|msg] -> [rsum|zsum|i_n|h_n]
    int r = bid - 513;
    for (int c = j; c < 512; c += 256) {
      float v;
      if (r < 128) v = (c < 384) ? W_ih[(size_t)r * 384 + c] : 0.f;
      else {
        int rm = r - 128;
        v = (c < 256) ? W_hh[(size_t)rm * 384 + c]
                      : (c < 384 ? 0.f : W_hh[(size_t)rm * 384 + 256 + (c - 384)]);
      }
      WgruCat[(size_t)r * 512 + c] = v;
    }
  } else if (bid == 769) {               // bgru
    bgru[j] = b_ih[j] + b_hh[j];                      // rsum/zsum biases (j<256)
    int c1 = j + 256;
    bgru[c1] = (c1 < 384) ? b_ih[c1] : b_hh[c1 - 128]; // i_n / h_n biases
  } else {                               // bid 770..869: zero cnt+cursor (2N ints)
    int g = ((bid - 770) * 256 + j) * 4;
    if (g < 2 * NN) *reinterpret_cast<int4*>(zint + g) = make_int4(0, 0, 0, 0);
  }
}

// ---------- K2: weight pack (blocks 0..39) + edge histogram (40..821); 1024 thr ----------
__global__ __launch_bounds__(1024) void pack_hist(
    const float* __restrict__ WcatQ, const float* __restrict__ WcatKV,
    const float* __restrict__ Wbig, const float* __restrict__ WgruCat,
    unsigned short* __restrict__ pQ, unsigned short* __restrict__ pKV,
    unsigned short* __restrict__ pBig, unsigned short* __restrict__ pGRU,
    const int* __restrict__ edges, int* __restrict__ cnt) {
  const int bid = blockIdx.x, tid = threadIdx.x;
  if (bid < 40) {
    int idx = bid * 1024 + tid;          // 0..40959
    const float* W; unsigned short* P; int KK, Nc;
    if (idx < 8192)       { W = WcatQ;   P = pQ;   KK = 128; Nc = 512; }
    else if (idx < 16384) { W = WcatKV;  P = pKV;  KK = 128; Nc = 512; idx -= 8192; }
    else if (idx < 24576) { W = Wbig;    P = pBig; KK = 512; Nc = 128; idx -= 16384; }
    else                  { W = WgruCat; P = pGRU; KK = 256; Nc = 512; idx -= 24576; }
    int nbs = Nc >> 4;
    int lane = idx & 63;
    int pair = idx >> 6;
    int kb = pair / nbs, nb = pair - kb * nbs;
    int kbase = kb * 32 + (lane >> 4) * 8;
    int col = nb * 16 + (lane & 15);
    unsigned short o[8];
#pragma unroll
    for (int j = 0; j < 8; ++j) o[j] = f2bf(W[(size_t)(kbase + j) * Nc + col]);
    *reinterpret_cast<bf16x8*>(P + (size_t)idx * 8) = *reinterpret_cast<bf16x8*>(o);
  } else {
    int e = (bid - 40) * 1024 + tid;
    if (e < EE) atomicAdd(&cnt[edges[EE + e]], 1);
  }
}

// ---------- K3: per-chunk inclusive scan (49 blocks x 1024, coalesced) ----------
__global__ __launch_bounds__(1024) void scan_partial(const int* __restrict__ cnt,
                                                     int* __restrict__ basep,
                                                     int* __restrict__ bsum) {
  __shared__ int sd[1024];
  int t = threadIdx.x, g = blockIdx.x * 1024 + t;
  int v = (g < NN) ? cnt[g] : 0;
  sd[t] = v;
  __syncthreads();
  for (int d = 1; d < 1024; d <<= 1) {
    int add = (t >= d) ? sd[t - d] : 0;
    __syncthreads();
    sd[t] += add;
    __syncthreads();
  }
  if (g < NN) basep[g] = sd[t] - v;
  if (t == 1023) bsum[blockIdx.x] = sd[1023];
}

// ---------- K4: finalize scan — per-block redundant bsum prefix + add ----------
__global__ __launch_bounds__(1024) void scan_final(const int* __restrict__ bsum,
                                                   const int* __restrict__ basep,
                                                   int* __restrict__ base) {
  __shared__ int s_off;
  const int bid = blockIdx.x, tid = threadIdx.x;
  if (tid < 64) {
    int v = (tid < 49) ? bsum[tid] : 0;
    int incl = v;
#pragma unroll
    for (int off = 1; off < 64; off <<= 1) {
      int o = __shfl_up(incl, off);
      if (tid >= off) incl += o;
    }
    int ex = (bid == 0) ? 0 : __shfl(incl, bid - 1);
    if (tid == 0) s_off = ex;
  }
  __syncthreads();
  int g = bid * 1024 + tid;
  if (g < NN) base[g] = basep[g] + s_off;
  if (bid == 48 && tid == 0) base[NN] = EE;
}

// ---------- MFMA bf16 GEMM body; OUT: 1=bf16, 2=f32+bf16; AF32: A is fp32 ----------
template <int OUT, int AF32, int NF, int EMITA>
__device__ __forceinline__ void gemm_body(
    int bx, int by, const void* __restrict__ Av, const unsigned short* __restrict__ Wp,
    const float* __restrict__ bias, float* __restrict__ C,
    unsigned short* __restrict__ Cbf, unsigned short* __restrict__ Abf,
    int M, int Arows, int K, int Nc) {
  const int wid = threadIdx.x >> 6, lane = threadIdx.x & 63;
  const int m0 = by * 64 + wid * 16;
  const int nb0 = bx * NF;
  const int nbs = Nc >> 4;
  const int row = m0 + (lane & 15);
  const int arow = min(row, Arows - 1);
  const int kq = lane >> 4;
  f32x4 acc[NF];
#pragma unroll
  for (int nf = 0; nf < NF; ++nf) acc[nf] = 0.f;
  const int nkb = K >> 5;
  for (int kb = 0; kb < nkb; ++kb) {
    bf16x8 a;
    if (AF32) {
      const float* ap = (const float*)Av + (size_t)arow * K + kb * 32 + kq * 8;
      const float4 f0 = *(const float4*)ap;
      const float4 f1 = *(const float4*)(ap + 4);
      unsigned short t[8] = {f2bf(f0.x), f2bf(f0.y), f2bf(f0.z), f2bf(f0.w),
                             f2bf(f1.x), f2bf(f1.y), f2bf(f1.z), f2bf(f1.w)};
      a = *reinterpret_cast<bf16x8*>(t);
      if (EMITA) {
        if (bx == 0)
          *reinterpret_cast<bf16x8*>(Abf + (size_t)arow * K + kb * 32 + kq * 8) = a;
      }
    } else {
      a = *reinterpret_cast<const bf16x8*>(
          (const unsigned short*)Av + (size_t)arow * K + kb * 32 + kq * 8);
    }
#pragma unroll
    for (int nf = 0; nf < NF; ++nf) {
      bf16x8 b = *reinterpret_cast<const bf16x8*>(
          Wp + ((size_t)(kb * nbs + nb0 + nf) * 64 + lane) * 8);
      acc[nf] = __builtin_amdgcn_mfma_f32_16x16x32_bf16(a, b, acc[nf], 0, 0, 0);
    }
  }
  const int crow0 = m0 + (lane >> 4) * 4;
  const int ccol = lane & 15;
#pragma unroll
  for (int nf = 0; nf < NF; ++nf) {
    const float bv = bias[(nb0 + nf) * 16 + ccol];
#pragma unroll
    for (int r = 0; r < 4; ++r) {
      float v = acc[nf][r] + bv;
      float vp = __shfl_xor(v, 1);
      const int rr = crow0 + r;
      if (rr < M) {
        if (OUT == 2)
          C[(size_t)rr * Nc + (nb0 + nf) * 16 + ccol] = v;
        if (!(lane & 1)) {
          ushort2 o;
          o.x = f2bf(v);
          o.y = f2bf(vp);
          *reinterpret_cast<ushort2*>(Cbf + (size_t)rr * Nc +
                                      (nb0 + nf) * 16 + (ccol & ~1)) = o;
        }
      }
    }
  }
}

template <int OUT, int AF32, int NF, int EMITA>
__global__ __launch_bounds__(256) void gemm_mfma(
    const void* __restrict__ Av, const unsigned short* __restrict__ Wp,
    const float* __restrict__ bias, float* __restrict__ C,
    unsigned short* __restrict__ Cbf, unsigned short* __restrict__ Abf,
    int M, int Arows, int K, int Nc) {
  gemm_body<OUT, AF32, NF, EMITA>(blockIdx.x, blockIdx.y, Av, Wp, bias, C, Cbf,
                                  Abf, M, Arows, K, Nc);
}

// ---------- K5: scatter (blocks 0..3124) + projQQ (..6252) + projKV (..9380) ----------
__global__ __launch_bounds__(256) void scatter_proj(
    const int* __restrict__ edges, const int* __restrict__ base,
    int* __restrict__ cursor, int2* __restrict__ epairs,
    const float* __restrict__ x0, const float* __restrict__ x1,
    const unsigned short* __restrict__ pQ, const unsigned short* __restrict__ pKV,
    const float* __restrict__ bcatQ, const float* __restrict__ bcatKV,
    unsigned short* __restrict__ QQbf, unsigned short* __restrict__ KVbf,
    unsigned short* __restrict__ x0bf) {
  const int bid = blockIdx.x;
  if (bid < 3125) {
    int e = bid * 256 + threadIdx.x;
    int s = edges[e];
    int d = edges[EE + e];
    int pos = base[d] + atomicAdd(&cursor[d], 1);
    epairs[pos] = make_int2(e, s);
  } else if (bid < 6253) {
    int pb = bid - 3125;
    gemm_body<1, 1, 8, 1>(pb & 3, pb >> 2, x0, pQ, bcatQ, nullptr, QQbf, x0bf,
                          NN, NN, 128, 512);
  } else {
    int pb = bid - 6253;
    gemm_body<1, 1, 8, 0>(pb & 3, pb >> 2, x1, pKV, bcatKV, nullptr, KVbf, nullptr,
                          NN, NN, 128, 512);
  }
}

// ---------- K6: fused attention: one wave per node, half-wave per edge ----------
__global__ __launch_bounds__(256) void attn_wave_kernel(
    const float* __restrict__ edge_attr, const unsigned short* __restrict__ QQbf,
    const unsigned short* __restrict__ KVbf, const int* __restrict__ base,
    const int2* __restrict__ epairs, unsigned short* __restrict__ aggbf) {
  const int wid = threadIdx.x >> 6, lane = threadIdx.x & 63;
  const int n = blockIdx.x * 4 + wid;
  if (n >= NN) return;
  const int hh = lane >> 5;            // which edge of the pair
  const int l = lane & 31;             // elem group: 4 elems per 128-block
  const unsigned short* qp = QQbf + (size_t)n * 512 + 4 * l;
  const float4 q0 = bf2f4(*(const ushort4*)(qp));
  const float4 q1 = bf2f4(*(const ushort4*)(qp + 128));
  const float4 w0 = bf2f4(*(const ushort4*)(qp + 256));
  const float4 w1 = bf2f4(*(const ushort4*)(qp + 384));
  const int beg = base[n], end = base[n + 1];
  float s0 = 0.f, s1 = 0.f;
  float4 ae0 = {0.f, 0.f, 0.f, 0.f}, ae1 = {0.f, 0.f, 0.f, 0.f};
  float4 av0 = {0.f, 0.f, 0.f, 0.f}, av1 = {0.f, 0.f, 0.f, 0.f};
  const float SC = 0.08838834764831845f;
  for (int p = beg; p < end; p += 2) {
    const int pe = min(p + hh, end - 1);
    const bool act = (p + hh < end);
    const int2 es = epairs[pe];
    const fv4 eav = __builtin_nontemporal_load(
        (const fv4*)(edge_attr + (size_t)es.x * 128 + 4 * l));
    const float4 ea = {eav.x, eav.y, eav.z, eav.w};
    const unsigned short* kp = KVbf + (size_t)es.y * 512 + 4 * l;
    const float4 k0 = bf2f4(*(const ushort4*)(kp));
    const float4 k1 = bf2f4(*(const ushort4*)(kp + 128));
    const float4 v0 = bf2f4(*(const ushort4*)(kp + 256));
    const float4 v1 = bf2f4(*(const ushort4*)(kp + 384));
    float p0 = ea.x * w0.x + ea.y * w0.y + ea.z * w0.z + ea.w * w0.w
             + q0.x * k0.x + q0.y * k0.y + q0.z * k0.z + q0.w * k0.w;
    float p1 = ea.x * w1.x + ea.y * w1.y + ea.z * w1.z + ea.w * w1.w
             + q1.x * k1.x + q1.y * k1.y + q1.z * k1.z + q1.w * k1.w;
#pragma unroll
    for (int off = 16; off; off >>= 1) {
      p0 += __shfl_xor(p0, off);
      p1 += __shfl_xor(p1, off);
    }
    float a0 = p0 * SC; a0 = (a0 < 0.f) ? 0.2f * a0 : a0;
    float a1 = p1 * SC; a1 = (a1 < 0.f) ? 0.2f * a1 : a1;
    const float x0 = act ? __expf(a0) : 0.f;
    const float x1 = act ? __expf(a1) : 0.f;
    s0 += x0; s1 += x1;
    ae0.x += x0 * ea.x; ae0.y += x0 * ea.y; ae0.z += x0 * ea.z; ae0.w += x0 * ea.w;
    ae1.x += x1 * ea.x; ae1.y += x1 * ea.y; ae1.z += x1 * ea.z; ae1.w += x1 * ea.w;
    av0.x += x0 * v0.x; av0.y += x0 * v0.y; av0.z += x0 * v0.z; av0.w += x0 * v0.w;
    av1.x += x1 * v1.x; av1.y += x1 * v1.y; av1.z += x1 * v1.z; av1.w += x1 * v1.w;
  }
  // combine the two half-wave accumulators
  s0 += __shfl_xor(s0, 32); s1 += __shfl_xor(s1, 32);
  ae0.x += __shfl_xor(ae0.x, 32); ae0.y += __shfl_xor(ae0.y, 32);
  ae0.z += __shfl_xor(ae0.z, 32); ae0.w += __shfl_xor(ae0.w, 32);
  ae1.x += __shfl_xor(ae1.x, 32); ae1.y += __shfl_xor(ae1.y, 32);
  ae1.z += __shfl_xor(ae1.z, 32); ae1.w += __shfl_xor(ae1.w, 32);
  av0.x += __shfl_xor(av0.x, 32); av0.y += __shfl_xor(av0.y, 32);
  av0.z += __shfl_xor(av0.z, 32); av0.w += __shfl_xor(av0.w, 32);
  av1.x += __shfl_xor(av1.x, 32); av1.y += __shfl_xor(av1.y, 32);
  av1.z += __shfl_xor(av1.z, 32); av1.w += __shfl_xor(av1.w, 32);
  const float i0 = 1.f / (s0 + 1e-16f), i1 = 1.f / (s1 + 1e-16f);
  if (hh == 0) {
    unsigned short* op = aggbf + (size_t)n * 512 + 4 * l;
    ushort4 o;
    o.x = f2bf(ae0.x * i0); o.y = f2bf(ae0.y * i0);
    o.z = f2bf(ae0.z * i0); o.w = f2bf(ae0.w * i0);
    *(ushort4*)op = o;
    o.x = f2bf(ae1.x * i1); o.y = f2bf(ae1.y * i1);
    o.z = f2bf(ae1.z * i1); o.w = f2bf(ae1.w * i1);
    *(ushort4*)(op + 128) = o;
    o.x = f2bf(av0.x * i0); o.y = f2bf(av0.y * i0);
    o.z = f2bf(av0.z * i0); o.w = f2bf(av0.w * i0);
    *(ushort4*)(op + 256) = o;
    o.x = f2bf(av1.x * i1); o.y = f2bf(av1.y * i1);
    o.z = f2bf(av1.z * i1); o.w = f2bf(av1.w * i1);
    *(ushort4*)(op + 384) = o;
  }
}

// ---------- K8: fused GRU: [x0|msg] @ WgruCat -> gates -> out ----------
// h term read from msgbf (bf16) — msgf eliminated.
__global__ __launch_bounds__(256) void gru_fused(
    const unsigned short* __restrict__ x0bf, const unsigned short* __restrict__ msgbf,
    const unsigned short* __restrict__ pGRU, const float* __restrict__ bgru,
    float* __restrict__ out) {
  const int wid = threadIdx.x >> 6, lane = threadIdx.x & 63;
  const int m0 = blockIdx.y * 64 + wid * 16;
  const int xq = blockIdx.x;           // output-dim quarter: d in [xq*32, xq*32+32)
  const int row = m0 + (lane & 15);
  const int ar = min(row, NN - 1);
  const int kq = lane >> 4;
  f32x4 acc[4][2];
#pragma unroll
  for (int g = 0; g < 4; ++g)
#pragma unroll
    for (int f = 0; f < 2; ++f) acc[g][f] = 0.f;
  for (int kb = 0; kb < 8; ++kb) {
    bf16x8 a;
    if (kb < 4) {
      a = *reinterpret_cast<const bf16x8*>(x0bf + (size_t)ar * 128 +
                                           kb * 32 + kq * 8);
    } else {
      a = *reinterpret_cast<const bf16x8*>(msgbf + (size_t)ar * 128 +
                                           (kb - 4) * 32 + kq * 8);
    }
#pragma unroll
    for (int g = 0; g < 4; ++g)
#pragma unroll
      for (int f = 0; f < 2; ++f) {
        const int nf = g * 8 + xq * 2 + f;
        bf16x8 b = *reinterpret_cast<const bf16x8*>(
            pGRU + ((size_t)(kb * 32 + nf) * 64 + lane) * 8);
        acc[g][f] = __builtin_amdgcn_mfma_f32_16x16x32_bf16(a, b, acc[g][f], 0, 0, 0);
      }
  }
  const int crow0 = m0 + (lane >> 4) * 4;
  const int ccol = lane & 15;
#pragma unroll
  for (int f = 0; f < 2; ++f) {
    const int d = xq * 32 + f * 16 + ccol;
    const float brs = bgru[d], bzs = bgru[128 + d];
    const float bin = bgru[256 + d], bhn = bgru[384 + d];
#pragma unroll
    for (int r = 0; r < 4; ++r) {
      const int rr = crow0 + r;
      if (rr < NN) {
        const float rs = acc[0][f][r] + brs;
        const float zs = acc[1][f][r] + bzs;
        const float iv = acc[2][f][r] + bin;
        const float hv = acc[3][f][r] + bhn;
        const float rg = 1.f / (1.f + __expf(-rs));
        const float zg = 1.f / (1.f + __expf(-zs));
        const float ng = tanhf(iv + rg * hv);
        const float h = __uint_as_float(
            (unsigned)msgbf[(size_t)rr * 128 + d] << 16);
        out[(size_t)rr * 128 + d] = (1.f - zg) * ng + zg * h;
      }
    }
  }
}

extern "C" void kernel_launch(void* const* d_in, const int* in_sizes, int n_in,
                              void* d_out, int out_size, void* d_ws, size_t ws_size,
                              hipStream_t stream) {
  const float* x0 = (const float*)d_in[0];
  const float* x1 = (const float*)d_in[1];
  const float* edge_attr = (const float*)d_in[2];
  const int* edges = (const int*)d_in[3];
  const float* Wq = (const float*)d_in[5];
  const float* bq = (const float*)d_in[6];
  const float* Wk = (const float*)d_in[7];
  const float* bk = (const float*)d_in[8];
  const float* Wv = (const float*)d_in[9];
  const float* bv = (const float*)d_in[10];
  const float* Wo = (const float*)d_in[11];
  const float* bo = (const float*)d_in[12];
  const float* W_ih = (const float*)d_in[13];
  const float* b_ih = (const float*)d_in[14];
  const float* W_hh = (const float*)d_in[15];
  const float* b_hh = (const float*)d_in[16];
  float* out = (float*)d_out;
  float* wsf = (float*)d_ws;

  unsigned short* QQbf  = (unsigned short*)(wsf + OFF_QQBF);
  unsigned short* KVbf  = (unsigned short*)(wsf + OFF_KVBF);
  unsigned short* aggbf = (unsigned short*)(wsf + OFF_AGGBF);
  unsigned short* msgbf = (unsigned short*)(wsf + OFF_MSGBF);
  unsigned short* x0bf  = (unsigned short*)(wsf + OFF_X0BF);
  int* ip    = (int*)(wsf + OFF_INT);
  int* cntb  = ip;                       // N
  int* curb  = ip + NN;                  // N
  int* bpart = ip + 2 * NN;              // N
  int* baseb = ip + 3 * NN;              // N+1
  int* bsumb = ip + 4 * NN + 1;          // 64
  int2* epairs = (int2*)(ip + 4 * NN + 130);   // 2E ints, 8B aligned
  float* WcatQ  = wsf + OFF_WCATQ;
  float* WcatKV = wsf + OFF_WCATKV;
  float* Wbigb  = wsf + OFF_WBIG;
  float* WgruC  = wsf + OFF_WGRU;
  float* bcatQ  = wsf + OFF_BCATQ;
  float* bcatKV = wsf + OFF_BCATKV;
  float* bgru   = wsf + OFF_BGRU;
  unsigned short* pQ   = (unsigned short*)(wsf + OFF_PQ);
  unsigned short* pKV  = (unsigned short*)(wsf + OFF_PKV);
  unsigned short* pBig = (unsigned short*)(wsf + OFF_PBIG);
  unsigned short* pGRU = (unsigned short*)(wsf + OFF_PGRU);

  // K1: weight prep + zero sort counters
  prep_all<<<870, 256, 0, stream>>>(Wq, bq, Wk, bk, Wv, bv, Wo, W_ih, b_ih,
                                    W_hh, b_hh, WcatQ, bcatQ, WcatKV, bcatKV,
                                    Wbigb, WgruC, bgru, ip);
  // K2: pack weights + histogram
  pack_hist<<<822, 1024, 0, stream>>>(WcatQ, WcatKV, Wbigb, WgruC,
                                      pQ, pKV, pBig, pGRU, edges, cntb);
  // K3/K4: two-level coalesced scan
  scan_partial<<<49, 1024, 0, stream>>>(cntb, bpart, bsumb);
  scan_final<<<49, 1024, 0, stream>>>(bsumb, bpart, baseb);
  // K5: scatter + both projection GEMMs
  scatter_proj<<<9381, 256, 0, stream>>>(edges, baseb, curb, epairs,
                                         x0, x1, pQ, pKV, bcatQ, bcatKV,
                                         QQbf, KVbf, x0bf);
  // K6: fused attention
  attn_wave_kernel<<<(NN + 3) / 4, 256, 0, stream>>>(edge_attr, QQbf, KVbf,
                                                     baseb, epairs, aggbf);
  // K7: msg = aggbf @ pBig + bo (bf16 out only)
  gemm_mfma<1, 0, 4, 0><<<dim3(2, MPAD / 64), 256, 0, stream>>>(
      aggbf, pBig, bo, nullptr, msgbf, nullptr, NN, NN, 512, 128);
  // K8: fused GRU -> out
  gru_fused<<<dim3(4, MPAD / 64), 256, 0, stream>>>(x0bf, msgbf, pGRU, bgru, out);
}